// Round 19
// baseline (22246.915 us; speedup 1.0000x reference)
//
#include <hip/hip_runtime.h>
#include <hip/hip_fp16.h>

// ---------------------------------------------------------------------------
// 2-layer LSTM (B=256, T=256, D=128, H=1024) + final Linear(H->128).
// Persistent kernel, one phase per timestep, flag-array grid barrier +
// single-L2-inv-per-XCD (R15/R18 protocol). K-loop = R13 asm ring-8.
//
// R19: MARGINAL-COST ABLATION. The whole GEMM pipeline runs TWICE per
// phase (independent accumulator sets, merged as (a0+a1)*0.5 — bitwise
// exact). Rep-2 re-reads the same data warm. Discriminates:
//   throughput-bound -> ~2x dur; unique-data/miss-storm -> ~+15%;
//   fixed overhead -> unchanged.
// ---------------------------------------------------------------------------

#define Bq 256
#define Hq 1024

typedef _Float16 half8 __attribute__((ext_vector_type(8)));
typedef float    floatx4 __attribute__((ext_vector_type(4)));

#define N_W1 8388608LL   // 128 cb * 65536  ([ks64][kb4][n2][jj16][e8])
#define N_W0 4718592LL   // 128 cb * 36864  ([ks36][kb4][n2][jj16][e8])
#define N_XH 8388608LL   // T*B*D
#define N_H  262144LL    // B*H
#define BH   262144

// ws byte offsets
#define OFF_W1 0LL
#define OFF_W0 16777216LL
#define OFF_XH 26214400LL
#define OFF_BA 42991616LL
#define OFF_BB 44040192LL
#define OFF_HF 45088768LL
#define OFF_SY 46137344LL
#define REQ_WS 46139392LL   // OFF_SY + 2048

// ---------------------------------------------------------------------------
__global__ void ws_sentinel_kernel(float* __restrict__ out, int n, float v)
{
    int i = blockIdx.x * blockDim.x + threadIdx.x;
    if (i < n) out[i] = v;
}

// ---------------------------------------------------------------------------
__global__ void prep_kernel(const float* __restrict__ x, const float* __restrict__ h0,
                            const float* __restrict__ Wih0, const float* __restrict__ Whh0,
                            const float* __restrict__ Wih1, const float* __restrict__ Whh1,
                            _Float16* __restrict__ w1p, _Float16* __restrict__ w0p,
                            _Float16* __restrict__ xh,
                            _Float16* __restrict__ bufA, _Float16* __restrict__ bufB,
                            unsigned* __restrict__ sync)
{
    long long gid = (long long)blockIdx.x * blockDim.x + threadIdx.x;
    if (gid < 512) sync[gid] = 0u;   // [0..255] global flags, [256..511] xcdgo

    if (gid < N_W1) {
        // [cb][ks][kb][n][jj][e]; gate-col row = (2n + jj>>3)*1024 + cb*8 + (jj&7)
        long long i = gid;
        int e  = (int)(i & 7);
        int jj = (int)((i >> 3) & 15);
        int n  = (int)((i >> 7) & 1);
        int kb = (int)((i >> 8) & 3);
        int ks = (int)((i >> 10) & 63);
        int cb = (int)(i >> 16);
        int row = (2 * n + (jj >> 3)) * 1024 + cb * 8 + (jj & 7);
        int k = ks * 32 + kb * 8 + e;
        float v = (k < 1024) ? Wih1[(size_t)row * 1024 + k]
                             : Whh1[(size_t)row * 1024 + (k - 1024)];
        w1p[i] = (_Float16)v;
    } else if (gid < N_W1 + N_W0) {
        long long i = gid - N_W1;
        int cb = (int)(i / 36864LL);
        int r  = (int)(i - (long long)cb * 36864LL);
        int ks = r >> 10;
        int kb = (r >> 8) & 3;
        int n  = (r >> 7) & 1;
        int jj = (r >> 3) & 15;
        int e  = r & 7;
        int row = (2 * n + (jj >> 3)) * 1024 + cb * 8 + (jj & 7);
        int k = ks * 32 + kb * 8 + e;
        float v = (k < 128) ? Wih0[(size_t)row * 128 + k]
                            : Whh0[(size_t)row * 1024 + (k - 128)];
        w0p[i] = (_Float16)v;
    } else if (gid < N_W1 + N_W0 + N_XH) {
        long long i = gid - N_W1 - N_W0;
        // xh[t][b][d] = x[b][t][d]
        int d = (int)(i & 127);
        int b = (int)((i >> 7) & 255);
        int t = (int)(i >> 15);
        xh[i] = (_Float16)x[((size_t)b * 256 + t) * 128 + d];
    } else if (gid < N_W1 + N_W0 + N_XH + N_H) {
        long long i = gid - N_W1 - N_W0 - N_XH;
        _Float16 v = (_Float16)h0[i];
        bufA[BH + i] = v;   // h_a(-1) parity 1
        bufB[BH + i] = v;   // h_b(-1) parity 1
    }
}

// ---------------------------------------------------------------------------
// Global flag-array barrier, fence-free (freshness handled by invround).
__device__ __forceinline__ void gridbar(unsigned* flags, int bid, unsigned target)
{
    __builtin_amdgcn_s_waitcnt(0);     // own write-through stores at IF
    __syncthreads();
    if (threadIdx.x == 0)
        __hip_atomic_store(flags + bid, target, __ATOMIC_RELAXED,
                           __HIP_MEMORY_SCOPE_AGENT);
    if (threadIdx.x < 256) {
        int guard = 0;
        while (__hip_atomic_load(flags + threadIdx.x, __ATOMIC_RELAXED,
                                 __HIP_MEMORY_SCOPE_AGENT) < target) {
            __builtin_amdgcn_s_sleep(1);
            if (++guard > (1 << 18)) break;        // safety: wrong, not wedged
        }
    }
    __syncthreads();
}

// ---------------------------------------------------------------------------
// Per-XCD single-L2-invalidate round (R15/R18 protocol, unchanged).
__device__ __forceinline__ void invround(unsigned* xcdgo, int slot, unsigned target)
{
    if (slot == 0) {
        if (threadIdx.x < 64) {
            __builtin_amdgcn_fence(__ATOMIC_ACQUIRE, "agent");   // buffer_inv sc1
            asm volatile("s_waitcnt vmcnt(0) lgkmcnt(0)" ::: "memory");
            if (threadIdx.x == 0)
                __hip_atomic_store(xcdgo, target, __ATOMIC_RELAXED,
                                   __HIP_MEMORY_SCOPE_AGENT);
        }
        __syncthreads();      // whole block (same CU) now fresh
    } else {
        if (threadIdx.x == 0) {
            int guard = 0;
            while (__hip_atomic_load(xcdgo, __ATOMIC_RELAXED,
                                     __HIP_MEMORY_SCOPE_AGENT) < target) {
                __builtin_amdgcn_s_sleep(1);
                if (++guard > (1 << 18)) break;
            }
        }
        __syncthreads();      // all waves gated until L2 is clean
        if (threadIdx.x == 0) {
            asm volatile("buffer_inv" ::: "memory");             // L1-only
            asm volatile("s_waitcnt vmcnt(0)" ::: "memory");
        }
        __syncthreads();
    }
}

#define MFMA16(A, Bv, C) __builtin_amdgcn_mfma_f32_16x16x32_f16((A), (Bv), (C), 0, 0, 0)

// ---- inline-asm pipelined K-step machinery (R13, unchanged) ---------------
#define PISSUE(I, P0, P1)                                           \
    asm volatile("global_load_dwordx4 %0, %2, off\n\t"              \
                 "global_load_dwordx4 %1, %3, off"                  \
                 : "=&v"(bf[I][0]), "=&v"(bf[I][1])                 \
                 : "v"(P0), "v"(P1) : "memory")

#define PSTEP14(I, P0, P1) do {                                     \
    half8 b0 = *(const half8*)(bp);                                 \
    half8 b1 = *(const half8*)(bp + 128);                           \
    asm volatile("s_waitcnt vmcnt(14)" ::: "memory");               \
    __builtin_amdgcn_sched_barrier(0);                              \
    acc[0][0] = MFMA16(bf[I][0], b0, acc[0][0]);                    \
    acc[0][1] = MFMA16(bf[I][0], b1, acc[0][1]);                    \
    acc[1][0] = MFMA16(bf[I][1], b0, acc[1][0]);                    \
    acc[1][1] = MFMA16(bf[I][1], b1, acc[1][1]);                    \
    bp += 1024;                                                     \
    PISSUE(I, P0, P1);                                              \
} while (0)

#define PSTEPW(I, NLIT) do {                                        \
    half8 b0 = *(const half8*)(bp);                                 \
    half8 b1 = *(const half8*)(bp + 128);                           \
    asm volatile("s_waitcnt vmcnt(" #NLIT ")" ::: "memory");        \
    __builtin_amdgcn_sched_barrier(0);                              \
    acc[0][0] = MFMA16(bf[I][0], b0, acc[0][0]);                    \
    acc[0][1] = MFMA16(bf[I][0], b1, acc[0][1]);                    \
    acc[1][0] = MFMA16(bf[I][1], b0, acc[1][0]);                    \
    acc[1][1] = MFMA16(bf[I][1], b1, acc[1][1]);                    \
    bp += 1024;                                                     \
} while (0)

__global__ void __launch_bounds__(512)
lstm_main(const _Float16* __restrict__ w1p, const _Float16* __restrict__ w0p,
          const _Float16* __restrict__ xh,
          _Float16* __restrict__ bufA, _Float16* __restrict__ bufB,
          float* __restrict__ hbF,
          const float* __restrict__ c0,
          const float* __restrict__ bih0, const float* __restrict__ bhh0,
          const float* __restrict__ bih1, const float* __restrict__ bhh1,
          const float* __restrict__ Wout, const float* __restrict__ bout,
          float* __restrict__ out, unsigned* __restrict__ sync)
{
    __shared__ _Float16 wlds[65536];   // 128 KiB

    const int tid  = threadIdx.x;
    const int lane = tid & 63;
    const int w    = tid >> 6;           // 0..7
    const int bid  = blockIdx.x;
    const int xcd  = bid & 7;
    const int slot = bid >> 3;           // 0..31
    const int isL1 = ((slot & 1) == 0);  // 16 L1 + 16 L0 blocks per XCD
    const int cb   = xcd * 16 + (slot >> 1);   // 0..127 column-block id
    const int jbase = cb * 8;
    const int jj = lane & 15;
    const int kb = lane >> 4;            // 0..3
    const int jh = jj & 7;
    const int lo = (jj < 8);
    const int rowbase = w * 32;          // wave's 32 batch rows

    unsigned* xcdgo = sync + 256 + xcd * 16;   // 64B-separated per-XCD flags

    // ---- load this block's weights into LDS (once) ----
    {
        const _Float16* src = isL1 ? (w1p + (size_t)cb * 65536)
                                   : (w0p + (size_t)cb * 36864);
        const int nch = isL1 ? 8192 : 4608;   // 16B chunks
        for (int i = tid; i < nch; i += 512)
            *(half8*)&wlds[(size_t)i * 8] = *(const half8*)&src[(size_t)i * 8];
    }
    __syncthreads();

    // ---- biases + cell-state init ----
    const float* bi  = isL1 ? bih1 : bih0;
    const float* bhp = isL1 ? bhh1 : bhh0;
    float bias[4];
#pragma unroll
    for (int g = 0; g < 4; ++g)
        bias[g] = bi[g * 1024 + jbase + jh] + bhp[g * 1024 + jbase + jh];

    float cc[2][4];
#pragma unroll
    for (int mf = 0; mf < 2; ++mf)
#pragma unroll
        for (int r = 0; r < 4; ++r)
            cc[mf][r] = c0[(size_t)(rowbase + mf * 16 + kb * 4 + r) * Hq + jbase + jh];

    floatx4 acc[2][2];
    half8 bf[8][2];                      // ring: 8 slots x 2 frags = 64 VGPRs

    for (int t = -1; t <= 255; ++t) {
        const int active = isL1 ? (t >= 0) : (t < 255);
        if (active) {
            floatx4 accS[2][2];
#pragma unroll 1
            for (int rep = 0; rep < 2; ++rep) {
#pragma unroll
                for (int mf = 0; mf < 2; ++mf)
#pragma unroll
                    for (int n = 0; n < 2; ++n)
                        acc[mf][n] = (floatx4){0.f, 0.f, 0.f, 0.f};

                const _Float16* bp = wlds + kb * 256 + jj * 8;

                if (isL1) {
                    // gates1(t) = h_a(t)@Wih1^T + h_b(t-1)@Whh1^T  (64 K-steps)
                    const _Float16* apA = bufA + (size_t)(t & 1) * BH
                                        + (size_t)(rowbase + jj) * Hq + kb * 8;
                    const _Float16* apB = bufB + (size_t)((t + 1) & 1) * BH
                                        + (size_t)(rowbase + jj) * Hq + kb * 8;
#define L1P0(S) (((S) < 32) ? (apA + (S) * 32) : (apB + ((S) - 32) * 32))
#define L1P1(S) (L1P0(S) + 16 * Hq)
#pragma unroll
                    for (int i = 0; i < 8; ++i) PISSUE(i, L1P0(i), L1P1(i));
#pragma unroll
                    for (int s = 0; s < 56; ++s)
                        PSTEP14(s & 7, L1P0(s + 8), L1P1(s + 8));
                    PSTEPW(0, 14); PSTEPW(1, 12); PSTEPW(2, 10); PSTEPW(3, 8);
                    PSTEPW(4, 6);  PSTEPW(5, 4);  PSTEPW(6, 2);  PSTEPW(7, 0);
#undef L1P0
#undef L1P1
                } else {
                    // gates0(t+1) = x(t+1)@Wih0^T + h_a(t)@Whh0^T  (36 K-steps)
                    const _Float16* apX = xh + (size_t)(t + 1) * (Bq * 128)
                                        + (size_t)(rowbase + jj) * 128 + kb * 8;
                    const _Float16* apA = bufA + (size_t)(t & 1) * BH
                                        + (size_t)(rowbase + jj) * Hq + kb * 8;
#define L0P0(S) (((S) < 4) ? (apX + (S) * 32) : (apA + ((S) - 4) * 32))
#define L0P1(S) (((S) < 4) ? (L0P0(S) + 16 * 128) : (L0P0(S) + 16 * Hq))
#pragma unroll
                    for (int i = 0; i < 8; ++i) PISSUE(i, L0P0(i), L0P1(i));
#pragma unroll
                    for (int s = 0; s < 28; ++s)
                        PSTEP14(s & 7, L0P0(s + 8), L0P1(s + 8));
                    PSTEPW(4, 14); PSTEPW(5, 12); PSTEPW(6, 10); PSTEPW(7, 8);
                    PSTEPW(0, 6);  PSTEPW(1, 4);  PSTEPW(2, 2);  PSTEPW(3, 0);
#undef L0P0
#undef L0P1
                }

                if (rep == 0) {
#pragma unroll
                    for (int mf = 0; mf < 2; ++mf)
#pragma unroll
                        for (int n = 0; n < 2; ++n)
                            accS[mf][n] = acc[mf][n];
                }
            }
            // merge: (rep0 + rep1) * 0.5 == rep result, bitwise exact
#pragma unroll
            for (int mf = 0; mf < 2; ++mf)
#pragma unroll
                for (int n = 0; n < 2; ++n)
#pragma unroll
                    for (int r = 0; r < 4; ++r)
                        acc[mf][n][r] = (acc[mf][n][r] + accS[mf][n][r]) * 0.5f;

            // ---- elementwise: gate-pair exchange + cell update + h store ----
            _Float16* hb = isL1 ? (bufB + (size_t)(t & 1) * BH)
                                : (bufA + (size_t)((t + 1) & 1) * BH);
            unsigned* hb32 = (unsigned*)hb;
#pragma unroll
            for (int mf = 0; mf < 2; ++mf) {
#pragma unroll
                for (int r = 0; r < 4; ++r) {
                    float o0 = acc[mf][0][r];       // lo: i, hi: f
                    float o1 = acc[mf][1][r];       // lo: g, hi: o
                    float p0 = __shfl_xor(o0, 8);
                    float p1 = __shfl_xor(o1, 8);
                    float gi = (lo ? o0 : p0) + bias[0];
                    float gf = (lo ? p0 : o0) + bias[1];
                    float gg = (lo ? o1 : p1) + bias[2];
                    float go = (lo ? p1 : o1) + bias[3];
                    float ii = 1.f / (1.f + expf(-gi));
                    float ff = 1.f / (1.f + expf(-gf));
                    float gt = tanhf(gg);
                    float oo = 1.f / (1.f + expf(-go));
                    float cn = ff * cc[mf][r] + ii * gt;
                    cc[mf][r] = cn;
                    float hn = oo * tanhf(cn);

                    union { _Float16 f; unsigned short u; } cv;
                    cv.f = (_Float16)hn;
                    int prt = __shfl_xor((int)cv.u, 1);   // neighbor j^1's bits
                    int row = rowbase + mf * 16 + kb * 4 + r;
                    if (lo && ((jh & 1) == 0)) {
                        unsigned word = (unsigned)cv.u | ((unsigned)prt << 16);
                        __hip_atomic_store(hb32 + (((size_t)row * Hq + jbase + jh) >> 1),
                                           word, __ATOMIC_RELAXED,
                                           __HIP_MEMORY_SCOPE_AGENT);
                    }
                    if (lo && isL1 && t == 255)
                        __hip_atomic_store(hbF + (size_t)row * Hq + jbase + jh,
                                           hn, __ATOMIC_RELAXED,
                                           __HIP_MEMORY_SCOPE_AGENT);
                }
            }
        }

        gridbar(sync, bid, (unsigned)(t + 2));
        invround(xcdgo, slot, (unsigned)(t + 2));
    }

    // ---- final: out[b][o] = b_out[o] + sum_k hbF[b][k] * Wout[o][k] ----
    // (t=255 invround already freshened L2/L1 for hbF's cached reads)
    int gid = bid * 512 + tid;
    if (gid < Bq * 128) {
        int b = gid >> 7, o = gid & 127;
        const floatx4* hr = (const floatx4*)(hbF + (size_t)b * Hq);
        const floatx4* wr = (const floatx4*)(Wout + (size_t)o * Hq);
        float s = bout[o];
#pragma unroll 4
        for (int k = 0; k < Hq / 4; ++k) {
            floatx4 hv = hr[k], wv = wr[k];
            s += hv[0] * wv[0] + hv[1] * wv[1] + hv[2] * wv[2] + hv[3] * wv[3];
        }
        out[gid] = s;
    }
}

// ---------------------------------------------------------------------------
extern "C" void kernel_launch(void* const* d_in, const int* in_sizes, int n_in,
                              void* d_out, int out_size, void* d_ws, size_t ws_size,
                              hipStream_t stream)
{
    (void)in_sizes; (void)n_in;
    float* out = (float*)d_out;

    if (ws_size < (size_t)REQ_WS) {
        float v = -(float)(ws_size >> 20);
        hipLaunchKernelGGL(ws_sentinel_kernel, dim3((out_size + 255) / 256), dim3(256),
                           0, stream, out, out_size, v);
        return;
    }

    const float* x    = (const float*)d_in[0];
    const float* h0   = (const float*)d_in[1];
    const float* c0   = (const float*)d_in[2];
    const float* Wih0 = (const float*)d_in[3];
    const float* Whh0 = (const float*)d_in[4];
    const float* bih0 = (const float*)d_in[5];
    const float* bhh0 = (const float*)d_in[6];
    const float* Wih1 = (const float*)d_in[7];
    const float* Whh1 = (const float*)d_in[8];
    const float* bih1 = (const float*)d_in[9];
    const float* bhh1 = (const float*)d_in[10];
    const float* Wout = (const float*)d_in[11];
    const float* bout = (const float*)d_in[12];

    char* ws = (char*)d_ws;
    _Float16* w1p  = (_Float16*)(ws + OFF_W1);
    _Float16* w0p  = (_Float16*)(ws + OFF_W0);
    _Float16* xh   = (_Float16*)(ws + OFF_XH);
    _Float16* bufA = (_Float16*)(ws + OFF_BA);
    _Float16* bufB = (_Float16*)(ws + OFF_BB);
    float*    hbF  = (float*)   (ws + OFF_HF);
    unsigned* sync = (unsigned*)(ws + OFF_SY);

    long long total = N_W1 + N_W0 + N_XH + N_H;   // 21,757,952 = 84992*256
    hipLaunchKernelGGL(prep_kernel, dim3((unsigned)(total / 256)), dim3(256), 0, stream,
                       x, h0, Wih0, Whh0, Wih1, Whh1, w1p, w0p, xh, bufA, bufB, sync);

    hipLaunchKernelGGL(lstm_main, dim3(256), dim3(512), 0, stream,
                       w1p, w0p, xh, bufA, bufB, hbF, c0,
                       bih0, bhh0, bih1, bhh1, Wout, bout, out, sync);
}

// Round 20
// 11073.354 us; speedup vs baseline: 2.0090x; 2.0090x over previous
//
#include <hip/hip_runtime.h>
#include <hip/hip_fp16.h>

// ---------------------------------------------------------------------------
// 2-layer LSTM (B=256, T=256, D=128, H=1024) + final Linear(H->128).
// Persistent kernel, one phase per timestep, flag-array grid barrier +
// single-L2-inv-per-XCD (R15/R18). K-loop = R13 asm ring-8 pipeline.
//
// R20: DECORRELATED DEMAND STREAM. All 256 blocks used to read the SAME
// 1MB h-state in the SAME order in lockstep after each barrier (R19's
// spill accident showed decorrelated traffic runs 9x faster on this exact
// structure). Two skews, zero semantic change:
//   - row skew: wave w of block b owns rows ((w+b)&7)*32
//   - K-order skew: block b starts its K traversal at (b*29)&63 (L1) /
//     (b*13)&31 on the h_a segment (L0); LDS weight offsets permuted
//     identically (fp32 sum-order change only).
// ---------------------------------------------------------------------------

#define Bq 256
#define Hq 1024

typedef _Float16 half8 __attribute__((ext_vector_type(8)));
typedef float    floatx4 __attribute__((ext_vector_type(4)));

#define N_W1 8388608LL   // 128 cb * 65536  ([ks64][kb4][n2][jj16][e8])
#define N_W0 4718592LL   // 128 cb * 36864  ([ks36][kb4][n2][jj16][e8])
#define N_XH 8388608LL   // T*B*D
#define N_H  262144LL    // B*H
#define BH   262144

// ws byte offsets
#define OFF_W1 0LL
#define OFF_W0 16777216LL
#define OFF_XH 26214400LL
#define OFF_BA 42991616LL
#define OFF_BB 44040192LL
#define OFF_HF 45088768LL
#define OFF_SY 46137344LL
#define REQ_WS 46139392LL   // OFF_SY + 2048

// ---------------------------------------------------------------------------
__global__ void ws_sentinel_kernel(float* __restrict__ out, int n, float v)
{
    int i = blockIdx.x * blockDim.x + threadIdx.x;
    if (i < n) out[i] = v;
}

// ---------------------------------------------------------------------------
__global__ void prep_kernel(const float* __restrict__ x, const float* __restrict__ h0,
                            const float* __restrict__ Wih0, const float* __restrict__ Whh0,
                            const float* __restrict__ Wih1, const float* __restrict__ Whh1,
                            _Float16* __restrict__ w1p, _Float16* __restrict__ w0p,
                            _Float16* __restrict__ xh,
                            _Float16* __restrict__ bufA, _Float16* __restrict__ bufB,
                            unsigned* __restrict__ sync)
{
    long long gid = (long long)blockIdx.x * blockDim.x + threadIdx.x;
    if (gid < 512) sync[gid] = 0u;   // [0..255] global flags, [256..511] xcdgo

    if (gid < N_W1) {
        // [cb][ks][kb][n][jj][e]; gate-col row = (2n + jj>>3)*1024 + cb*8 + (jj&7)
        long long i = gid;
        int e  = (int)(i & 7);
        int jj = (int)((i >> 3) & 15);
        int n  = (int)((i >> 7) & 1);
        int kb = (int)((i >> 8) & 3);
        int ks = (int)((i >> 10) & 63);
        int cb = (int)(i >> 16);
        int row = (2 * n + (jj >> 3)) * 1024 + cb * 8 + (jj & 7);
        int k = ks * 32 + kb * 8 + e;
        float v = (k < 1024) ? Wih1[(size_t)row * 1024 + k]
                             : Whh1[(size_t)row * 1024 + (k - 1024)];
        w1p[i] = (_Float16)v;
    } else if (gid < N_W1 + N_W0) {
        long long i = gid - N_W1;
        int cb = (int)(i / 36864LL);
        int r  = (int)(i - (long long)cb * 36864LL);
        int ks = r >> 10;
        int kb = (r >> 8) & 3;
        int n  = (r >> 7) & 1;
        int jj = (r >> 3) & 15;
        int e  = r & 7;
        int row = (2 * n + (jj >> 3)) * 1024 + cb * 8 + (jj & 7);
        int k = ks * 32 + kb * 8 + e;
        float v = (k < 128) ? Wih0[(size_t)row * 128 + k]
                            : Whh0[(size_t)row * 1024 + (k - 128)];
        w0p[i] = (_Float16)v;
    } else if (gid < N_W1 + N_W0 + N_XH) {
        long long i = gid - N_W1 - N_W0;
        // xh[t][b][d] = x[b][t][d]
        int d = (int)(i & 127);
        int b = (int)((i >> 7) & 255);
        int t = (int)(i >> 15);
        xh[i] = (_Float16)x[((size_t)b * 256 + t) * 128 + d];
    } else if (gid < N_W1 + N_W0 + N_XH + N_H) {
        long long i = gid - N_W1 - N_W0 - N_XH;
        _Float16 v = (_Float16)h0[i];
        bufA[BH + i] = v;   // h_a(-1) parity 1
        bufB[BH + i] = v;   // h_b(-1) parity 1
    }
}

// ---------------------------------------------------------------------------
// Global flag-array barrier, fence-free (freshness handled by invround).
__device__ __forceinline__ void gridbar(unsigned* flags, int bid, unsigned target)
{
    __builtin_amdgcn_s_waitcnt(0);     // own write-through stores at IF
    __syncthreads();
    if (threadIdx.x == 0)
        __hip_atomic_store(flags + bid, target, __ATOMIC_RELAXED,
                           __HIP_MEMORY_SCOPE_AGENT);
    if (threadIdx.x < 256) {
        int guard = 0;
        while (__hip_atomic_load(flags + threadIdx.x, __ATOMIC_RELAXED,
                                 __HIP_MEMORY_SCOPE_AGENT) < target) {
            __builtin_amdgcn_s_sleep(1);
            if (++guard > (1 << 18)) break;        // safety: wrong, not wedged
        }
    }
    __syncthreads();
}

// ---------------------------------------------------------------------------
// Per-XCD single-L2-invalidate round (R15/R18 protocol, unchanged).
__device__ __forceinline__ void invround(unsigned* xcdgo, int slot, unsigned target)
{
    if (slot == 0) {
        if (threadIdx.x < 64) {
            __builtin_amdgcn_fence(__ATOMIC_ACQUIRE, "agent");   // buffer_inv sc1
            asm volatile("s_waitcnt vmcnt(0) lgkmcnt(0)" ::: "memory");
            if (threadIdx.x == 0)
                __hip_atomic_store(xcdgo, target, __ATOMIC_RELAXED,
                                   __HIP_MEMORY_SCOPE_AGENT);
        }
        __syncthreads();      // whole block (same CU) now fresh
    } else {
        if (threadIdx.x == 0) {
            int guard = 0;
            while (__hip_atomic_load(xcdgo, __ATOMIC_RELAXED,
                                     __HIP_MEMORY_SCOPE_AGENT) < target) {
                __builtin_amdgcn_s_sleep(1);
                if (++guard > (1 << 18)) break;
            }
        }
        __syncthreads();      // all waves gated until L2 is clean
        if (threadIdx.x == 0) {
            asm volatile("buffer_inv" ::: "memory");             // L1-only
            asm volatile("s_waitcnt vmcnt(0)" ::: "memory");
        }
        __syncthreads();
    }
}

#define MFMA16(A, Bv, C) __builtin_amdgcn_mfma_f32_16x16x32_f16((A), (Bv), (C), 0, 0, 0)

// ---- inline-asm pipelined K-step machinery (skew-parameterized) -----------
#define PISSUE(I, P0, P1)                                           \
    asm volatile("global_load_dwordx4 %0, %2, off\n\t"              \
                 "global_load_dwordx4 %1, %3, off"                  \
                 : "=&v"(bf[I][0]), "=&v"(bf[I][1])                 \
                 : "v"(P0), "v"(P1) : "memory")

// consume slot I (weights at physical step PC), reissue addresses P0/P1
#define PSTEP14K(I, PC, P0, P1) do {                                \
    const _Float16* wb_ = wb + (size_t)(PC) * 1024;                 \
    half8 b0 = *(const half8*)(wb_);                                \
    half8 b1 = *(const half8*)(wb_ + 128);                          \
    asm volatile("s_waitcnt vmcnt(14)" ::: "memory");               \
    __builtin_amdgcn_sched_barrier(0);                              \
    acc[0][0] = MFMA16(bf[I][0], b0, acc[0][0]);                    \
    acc[0][1] = MFMA16(bf[I][0], b1, acc[0][1]);                    \
    acc[1][0] = MFMA16(bf[I][1], b0, acc[1][0]);                    \
    acc[1][1] = MFMA16(bf[I][1], b1, acc[1][1]);                    \
    PISSUE(I, P0, P1);                                              \
} while (0)

// drain step: consume slot I (weights at physical step PC), literal wait
#define PSTEPWK(I, PC, NLIT) do {                                   \
    const _Float16* wb_ = wb + (size_t)(PC) * 1024;                 \
    half8 b0 = *(const half8*)(wb_);                                \
    half8 b1 = *(const half8*)(wb_ + 128);                          \
    asm volatile("s_waitcnt vmcnt(" #NLIT ")" ::: "memory");        \
    __builtin_amdgcn_sched_barrier(0);                              \
    acc[0][0] = MFMA16(bf[I][0], b0, acc[0][0]);                    \
    acc[0][1] = MFMA16(bf[I][0], b1, acc[0][1]);                    \
    acc[1][0] = MFMA16(bf[I][1], b0, acc[1][0]);                    \
    acc[1][1] = MFMA16(bf[I][1], b1, acc[1][1]);                    \
} while (0)

__global__ void __launch_bounds__(512)
lstm_main(const _Float16* __restrict__ w1p, const _Float16* __restrict__ w0p,
          const _Float16* __restrict__ xh,
          _Float16* __restrict__ bufA, _Float16* __restrict__ bufB,
          float* __restrict__ hbF,
          const float* __restrict__ c0,
          const float* __restrict__ bih0, const float* __restrict__ bhh0,
          const float* __restrict__ bih1, const float* __restrict__ bhh1,
          const float* __restrict__ Wout, const float* __restrict__ bout,
          float* __restrict__ out, unsigned* __restrict__ sync)
{
    __shared__ _Float16 wlds[65536];   // 128 KiB

    const int tid  = threadIdx.x;
    const int lane = tid & 63;
    const int w    = tid >> 6;           // 0..7
    const int bid  = blockIdx.x;
    const int xcd  = bid & 7;
    const int slot = bid >> 3;           // 0..31
    const int isL1 = ((slot & 1) == 0);  // 16 L1 + 16 L0 blocks per XCD
    const int cb   = xcd * 16 + (slot >> 1);   // 0..127 column-block id
    const int jbase = cb * 8;
    const int jj = lane & 15;
    const int kb = lane >> 4;            // 0..3
    const int jh = jj & 7;
    const int lo = (jj < 8);
    const int rowbase = ((w + bid) & 7) * 32;   // ROW SKEW per block
    const int kskew = (bid * 29) & 63;          // K skew (L1, 64 steps)
    const int ksk32 = (bid * 13) & 31;          // K skew (L0 h_a, 32 steps)

    unsigned* xcdgo = sync + 256 + xcd * 16;   // 64B-separated per-XCD flags

    // ---- load this block's weights into LDS (once) ----
    {
        const _Float16* src = isL1 ? (w1p + (size_t)cb * 65536)
                                   : (w0p + (size_t)cb * 36864);
        const int nch = isL1 ? 8192 : 4608;   // 16B chunks
        for (int i = tid; i < nch; i += 512)
            *(half8*)&wlds[(size_t)i * 8] = *(const half8*)&src[(size_t)i * 8];
    }
    __syncthreads();

    // ---- biases + cell-state init ----
    const float* bi  = isL1 ? bih1 : bih0;
    const float* bhp = isL1 ? bhh1 : bhh0;
    float bias[4];
#pragma unroll
    for (int g = 0; g < 4; ++g)
        bias[g] = bi[g * 1024 + jbase + jh] + bhp[g * 1024 + jbase + jh];

    float cc[2][4];
#pragma unroll
    for (int mf = 0; mf < 2; ++mf)
#pragma unroll
        for (int r = 0; r < 4; ++r)
            cc[mf][r] = c0[(size_t)(rowbase + mf * 16 + kb * 4 + r) * Hq + jbase + jh];

    floatx4 acc[2][2];
    half8 bf[8][2];                      // ring: 8 slots x 2 frags = 64 VGPRs

    for (int t = -1; t <= 255; ++t) {
        const int active = isL1 ? (t >= 0) : (t < 255);
        if (active) {
#pragma unroll
            for (int mf = 0; mf < 2; ++mf)
#pragma unroll
                for (int n = 0; n < 2; ++n)
                    acc[mf][n] = (floatx4){0.f, 0.f, 0.f, 0.f};

            const _Float16* wb = wlds + kb * 256 + jj * 8;

            if (isL1) {
                // gates1(t) = h_a(t)@Wih1^T + h_b(t-1)@Whh1^T  (64 K-steps)
                const _Float16* apA = bufA + (size_t)(t & 1) * BH
                                    + (size_t)(rowbase + jj) * Hq + kb * 8;
                const _Float16* apB = bufB + (size_t)((t + 1) & 1) * BH
                                    + (size_t)(rowbase + jj) * Hq + kb * 8;
#define KP1(S) (((S) + kskew) & 63)
#define A1P(P) ((P) < 32 ? (apA + (size_t)(P) * 32) : (apB + (size_t)((P) - 32) * 32))
#define A1Q(P) (A1P(P) + 16 * Hq)
#pragma unroll
                for (int i = 0; i < 8; ++i) {
                    int p = KP1(i);
                    PISSUE(i, A1P(p), A1Q(p));
                }
#pragma unroll
                for (int s = 0; s < 56; ++s) {
                    int pc = KP1(s);
                    int pn = KP1(s + 8);
                    PSTEP14K(s & 7, pc, A1P(pn), A1Q(pn));
                }
                PSTEPWK(0, KP1(56), 14); PSTEPWK(1, KP1(57), 12);
                PSTEPWK(2, KP1(58), 10); PSTEPWK(3, KP1(59), 8);
                PSTEPWK(4, KP1(60), 6);  PSTEPWK(5, KP1(61), 4);
                PSTEPWK(6, KP1(62), 2);  PSTEPWK(7, KP1(63), 0);
#undef KP1
#undef A1P
#undef A1Q
            } else {
                // gates0(t+1) = x(t+1)@Wih0^T + h_a(t)@Whh0^T  (36 K-steps)
                const _Float16* apX = xh + (size_t)(t + 1) * (Bq * 128)
                                    + (size_t)(rowbase + jj) * 128 + kb * 8;
                const _Float16* apA = bufA + (size_t)(t & 1) * BH
                                    + (size_t)(rowbase + jj) * Hq + kb * 8;
#define KP0(S) ((S) < 4 ? (S) : (4 + (((S) - 4 + ksk32) & 31)))
#define A0P(P) ((P) < 4 ? (apX + (size_t)(P) * 32) : (apA + (size_t)((P) - 4) * 32))
#define A0Q(P) ((P) < 4 ? (apX + (size_t)(P) * 32 + 16 * 128) : (apA + (size_t)((P) - 4) * 32 + 16 * Hq))
#pragma unroll
                for (int i = 0; i < 8; ++i) {
                    int p = KP0(i);
                    PISSUE(i, A0P(p), A0Q(p));
                }
#pragma unroll
                for (int s = 0; s < 28; ++s) {
                    int pc = KP0(s);
                    int pn = KP0(s + 8);
                    PSTEP14K(s & 7, pc, A0P(pn), A0Q(pn));
                }
                PSTEPWK(4, KP0(28), 14); PSTEPWK(5, KP0(29), 12);
                PSTEPWK(6, KP0(30), 10); PSTEPWK(7, KP0(31), 8);
                PSTEPWK(0, KP0(32), 6);  PSTEPWK(1, KP0(33), 4);
                PSTEPWK(2, KP0(34), 2);  PSTEPWK(3, KP0(35), 0);
#undef KP0
#undef A0P
#undef A0Q
            }

            // ---- elementwise: gate-pair exchange + cell update + h store ----
            _Float16* hb = isL1 ? (bufB + (size_t)(t & 1) * BH)
                                : (bufA + (size_t)((t + 1) & 1) * BH);
            unsigned* hb32 = (unsigned*)hb;
#pragma unroll
            for (int mf = 0; mf < 2; ++mf) {
#pragma unroll
                for (int r = 0; r < 4; ++r) {
                    float o0 = acc[mf][0][r];       // lo: i, hi: f
                    float o1 = acc[mf][1][r];       // lo: g, hi: o
                    float p0 = __shfl_xor(o0, 8);
                    float p1 = __shfl_xor(o1, 8);
                    float gi = (lo ? o0 : p0) + bias[0];
                    float gf = (lo ? p0 : o0) + bias[1];
                    float gg = (lo ? o1 : p1) + bias[2];
                    float go = (lo ? p1 : o1) + bias[3];
                    float ii = 1.f / (1.f + expf(-gi));
                    float ff = 1.f / (1.f + expf(-gf));
                    float gt = tanhf(gg);
                    float oo = 1.f / (1.f + expf(-go));
                    float cn = ff * cc[mf][r] + ii * gt;
                    cc[mf][r] = cn;
                    float hn = oo * tanhf(cn);

                    union { _Float16 f; unsigned short u; } cv;
                    cv.f = (_Float16)hn;
                    int prt = __shfl_xor((int)cv.u, 1);   // neighbor j^1's bits
                    int row = rowbase + mf * 16 + kb * 4 + r;
                    if (lo && ((jh & 1) == 0)) {
                        unsigned word = (unsigned)cv.u | ((unsigned)prt << 16);
                        __hip_atomic_store(hb32 + (((size_t)row * Hq + jbase + jh) >> 1),
                                           word, __ATOMIC_RELAXED,
                                           __HIP_MEMORY_SCOPE_AGENT);
                    }
                    if (lo && isL1 && t == 255)
                        __hip_atomic_store(hbF + (size_t)row * Hq + jbase + jh,
                                           hn, __ATOMIC_RELAXED,
                                           __HIP_MEMORY_SCOPE_AGENT);
                }
            }
        }

        gridbar(sync, bid, (unsigned)(t + 2));
        invround(xcdgo, slot, (unsigned)(t + 2));
    }

    // ---- final: out[b][o] = b_out[o] + sum_k hbF[b][k] * Wout[o][k] ----
    // (t=255 invround already freshened L2/L1 for hbF's cached reads)
    int gid = bid * 512 + tid;
    if (gid < Bq * 128) {
        int b = gid >> 7, o = gid & 127;
        const floatx4* hr = (const floatx4*)(hbF + (size_t)b * Hq);
        const floatx4* wr = (const floatx4*)(Wout + (size_t)o * Hq);
        float s = bout[o];
#pragma unroll 4
        for (int k = 0; k < Hq / 4; ++k) {
            floatx4 hv = hr[k], wv = wr[k];
            s += hv[0] * wv[0] + hv[1] * wv[1] + hv[2] * wv[2] + hv[3] * wv[3];
        }
        out[gid] = s;
    }
}

// ---------------------------------------------------------------------------
extern "C" void kernel_launch(void* const* d_in, const int* in_sizes, int n_in,
                              void* d_out, int out_size, void* d_ws, size_t ws_size,
                              hipStream_t stream)
{
    (void)in_sizes; (void)n_in;
    float* out = (float*)d_out;

    if (ws_size < (size_t)REQ_WS) {
        float v = -(float)(ws_size >> 20);
        hipLaunchKernelGGL(ws_sentinel_kernel, dim3((out_size + 255) / 256), dim3(256),
                           0, stream, out, out_size, v);
        return;
    }

    const float* x    = (const float*)d_in[0];
    const float* h0   = (const float*)d_in[1];
    const float* c0   = (const float*)d_in[2];
    const float* Wih0 = (const float*)d_in[3];
    const float* Whh0 = (const float*)d_in[4];
    const float* bih0 = (const float*)d_in[5];
    const float* bhh0 = (const float*)d_in[6];
    const float* Wih1 = (const float*)d_in[7];
    const float* Whh1 = (const float*)d_in[8];
    const float* bih1 = (const float*)d_in[9];
    const float* bhh1 = (const float*)d_in[10];
    const float* Wout = (const float*)d_in[11];
    const float* bout = (const float*)d_in[12];

    char* ws = (char*)d_ws;
    _Float16* w1p  = (_Float16*)(ws + OFF_W1);
    _Float16* w0p  = (_Float16*)(ws + OFF_W0);
    _Float16* xh   = (_Float16*)(ws + OFF_XH);
    _Float16* bufA = (_Float16*)(ws + OFF_BA);
    _Float16* bufB = (_Float16*)(ws + OFF_BB);
    float*    hbF  = (float*)   (ws + OFF_HF);
    unsigned* sync = (unsigned*)(ws + OFF_SY);

    long long total = N_W1 + N_W0 + N_XH + N_H;   // 21,757,952 = 84992*256
    hipLaunchKernelGGL(prep_kernel, dim3((unsigned)(total / 256)), dim3(256), 0, stream,
                       x, h0, Wih0, Whh0, Wih1, Whh1, w1p, w0p, xh, bufA, bufB, sync);

    hipLaunchKernelGGL(lstm_main, dim3(256), dim3(512), 0, stream,
                       w1p, w0p, xh, bufA, bufB, hbF, c0,
                       bih0, bhh0, bih1, bhh1, Wout, bout, out, sync);
}

// Round 21
// 9509.489 us; speedup vs baseline: 2.3394x; 1.1645x over previous
//
#include <hip/hip_runtime.h>
#include <hip/hip_fp16.h>

// ---------------------------------------------------------------------------
// 2-layer LSTM (B=256, T=256, D=128, H=1024) + final Linear(H->128).
// Persistent kernel, one phase per timestep, flag-array grid barrier +
// single-L2-inv-per-XCD (R15/R18). K-loop = R13 asm ring-8 pipeline.
//
// R21: 2x-REPLICATED h-STATE (channel spreading). All 32 blocks of an XCD
// used to read the SAME cache line nearly simultaneously -> one L2 channel
// serves everything (R19/R20: decorrelated traffic runs 3-9x faster).
// Writers store h to TWO copies; readers pick copy (slot>>1)&1 -> same-line
// concurrency halves while the prefetch-friendly sequential K-sweep (which
// R20's skew destroyed) is preserved. Everything else = R18 (9.36 ms best).
// ---------------------------------------------------------------------------

#define Bq 256
#define Hq 1024

typedef _Float16 half8 __attribute__((ext_vector_type(8)));
typedef float    floatx4 __attribute__((ext_vector_type(4)));

#define N_W1 8388608LL   // 128 cb * 65536  ([ks64][kb4][n2][jj16][e8])
#define N_W0 4718592LL   // 128 cb * 36864  ([ks36][kb4][n2][jj16][e8])
#define N_XH 8388608LL   // T*B*D
#define N_H  262144LL    // B*H
#define BH   262144

// ws byte offsets (bufA/bufB are now [parity][copy] = 4 x 512 KB each)
#define OFF_W1 0LL
#define OFF_W0 16777216LL
#define OFF_XH 26214400LL
#define OFF_BA 42991616LL
#define OFF_BB 45088768LL
#define OFF_HF 47185920LL
#define OFF_SY 48234496LL
#define REQ_WS 48236544LL   // OFF_SY + 2048

// ---------------------------------------------------------------------------
__global__ void ws_sentinel_kernel(float* __restrict__ out, int n, float v)
{
    int i = blockIdx.x * blockDim.x + threadIdx.x;
    if (i < n) out[i] = v;
}

// ---------------------------------------------------------------------------
__global__ void prep_kernel(const float* __restrict__ x, const float* __restrict__ h0,
                            const float* __restrict__ Wih0, const float* __restrict__ Whh0,
                            const float* __restrict__ Wih1, const float* __restrict__ Whh1,
                            _Float16* __restrict__ w1p, _Float16* __restrict__ w0p,
                            _Float16* __restrict__ xh,
                            _Float16* __restrict__ bufA, _Float16* __restrict__ bufB,
                            unsigned* __restrict__ sync)
{
    long long gid = (long long)blockIdx.x * blockDim.x + threadIdx.x;
    if (gid < 512) sync[gid] = 0u;   // [0..255] global flags, [256..511] xcdgo

    if (gid < N_W1) {
        // [cb][ks][kb][n][jj][e]; gate-col row = (2n + jj>>3)*1024 + cb*8 + (jj&7)
        long long i = gid;
        int e  = (int)(i & 7);
        int jj = (int)((i >> 3) & 15);
        int n  = (int)((i >> 7) & 1);
        int kb = (int)((i >> 8) & 3);
        int ks = (int)((i >> 10) & 63);
        int cb = (int)(i >> 16);
        int row = (2 * n + (jj >> 3)) * 1024 + cb * 8 + (jj & 7);
        int k = ks * 32 + kb * 8 + e;
        float v = (k < 1024) ? Wih1[(size_t)row * 1024 + k]
                             : Whh1[(size_t)row * 1024 + (k - 1024)];
        w1p[i] = (_Float16)v;
    } else if (gid < N_W1 + N_W0) {
        long long i = gid - N_W1;
        int cb = (int)(i / 36864LL);
        int r  = (int)(i - (long long)cb * 36864LL);
        int ks = r >> 10;
        int kb = (r >> 8) & 3;
        int n  = (r >> 7) & 1;
        int jj = (r >> 3) & 15;
        int e  = r & 7;
        int row = (2 * n + (jj >> 3)) * 1024 + cb * 8 + (jj & 7);
        int k = ks * 32 + kb * 8 + e;
        float v = (k < 128) ? Wih0[(size_t)row * 128 + k]
                            : Whh0[(size_t)row * 1024 + (k - 128)];
        w0p[i] = (_Float16)v;
    } else if (gid < N_W1 + N_W0 + N_XH) {
        long long i = gid - N_W1 - N_W0;
        // xh[t][b][d] = x[b][t][d]
        int d = (int)(i & 127);
        int b = (int)((i >> 7) & 255);
        int t = (int)(i >> 15);
        xh[i] = (_Float16)x[((size_t)b * 256 + t) * 128 + d];
    } else if (gid < N_W1 + N_W0 + N_XH + N_H) {
        long long i = gid - N_W1 - N_W0 - N_XH;
        _Float16 v = (_Float16)h0[i];
        bufA[2 * BH + i] = v;   // h_a(-1) parity 1, copy 0
        bufA[3 * BH + i] = v;   // h_a(-1) parity 1, copy 1
        bufB[2 * BH + i] = v;   // h_b(-1) parity 1, copy 0
        bufB[3 * BH + i] = v;   // h_b(-1) parity 1, copy 1
    }
}

// ---------------------------------------------------------------------------
// Global flag-array barrier, fence-free (freshness handled by invround).
__device__ __forceinline__ void gridbar(unsigned* flags, int bid, unsigned target)
{
    __builtin_amdgcn_s_waitcnt(0);     // own write-through stores at IF
    __syncthreads();
    if (threadIdx.x == 0)
        __hip_atomic_store(flags + bid, target, __ATOMIC_RELAXED,
                           __HIP_MEMORY_SCOPE_AGENT);
    if (threadIdx.x < 256) {
        int guard = 0;
        while (__hip_atomic_load(flags + threadIdx.x, __ATOMIC_RELAXED,
                                 __HIP_MEMORY_SCOPE_AGENT) < target) {
            __builtin_amdgcn_s_sleep(1);
            if (++guard > (1 << 18)) break;        // safety: wrong, not wedged
        }
    }
    __syncthreads();
}

// ---------------------------------------------------------------------------
// Per-XCD single-L2-invalidate round (R15/R18 protocol, unchanged).
__device__ __forceinline__ void invround(unsigned* xcdgo, int slot, unsigned target)
{
    if (slot == 0) {
        if (threadIdx.x < 64) {
            __builtin_amdgcn_fence(__ATOMIC_ACQUIRE, "agent");   // buffer_inv sc1
            asm volatile("s_waitcnt vmcnt(0) lgkmcnt(0)" ::: "memory");
            if (threadIdx.x == 0)
                __hip_atomic_store(xcdgo, target, __ATOMIC_RELAXED,
                                   __HIP_MEMORY_SCOPE_AGENT);
        }
        __syncthreads();      // whole block (same CU) now fresh
    } else {
        if (threadIdx.x == 0) {
            int guard = 0;
            while (__hip_atomic_load(xcdgo, __ATOMIC_RELAXED,
                                     __HIP_MEMORY_SCOPE_AGENT) < target) {
                __builtin_amdgcn_s_sleep(1);
                if (++guard > (1 << 18)) break;
            }
        }
        __syncthreads();      // all waves gated until L2 is clean
        if (threadIdx.x == 0) {
            asm volatile("buffer_inv" ::: "memory");             // L1-only
            asm volatile("s_waitcnt vmcnt(0)" ::: "memory");
        }
        __syncthreads();
    }
}

#define MFMA16(A, Bv, C) __builtin_amdgcn_mfma_f32_16x16x32_f16((A), (Bv), (C), 0, 0, 0)

// ---- inline-asm pipelined K-step machinery (R13, unchanged) ---------------
#define PISSUE(I, P0, P1)                                           \
    asm volatile("global_load_dwordx4 %0, %2, off\n\t"              \
                 "global_load_dwordx4 %1, %3, off"                  \
                 : "=&v"(bf[I][0]), "=&v"(bf[I][1])                 \
                 : "v"(P0), "v"(P1) : "memory")

#define PSTEP14(I, P0, P1) do {                                     \
    half8 b0 = *(const half8*)(bp);                                 \
    half8 b1 = *(const half8*)(bp + 128);                           \
    asm volatile("s_waitcnt vmcnt(14)" ::: "memory");               \
    __builtin_amdgcn_sched_barrier(0);                              \
    acc[0][0] = MFMA16(bf[I][0], b0, acc[0][0]);                    \
    acc[0][1] = MFMA16(bf[I][0], b1, acc[0][1]);                    \
    acc[1][0] = MFMA16(bf[I][1], b0, acc[1][0]);                    \
    acc[1][1] = MFMA16(bf[I][1], b1, acc[1][1]);                    \
    bp += 1024;                                                     \
    PISSUE(I, P0, P1);                                              \
} while (0)

#define PSTEPW(I, NLIT) do {                                        \
    half8 b0 = *(const half8*)(bp);                                 \
    half8 b1 = *(const half8*)(bp + 128);                           \
    asm volatile("s_waitcnt vmcnt(" #NLIT ")" ::: "memory");        \
    __builtin_amdgcn_sched_barrier(0);                              \
    acc[0][0] = MFMA16(bf[I][0], b0, acc[0][0]);                    \
    acc[0][1] = MFMA16(bf[I][0], b1, acc[0][1]);                    \
    acc[1][0] = MFMA16(bf[I][1], b0, acc[1][0]);                    \
    acc[1][1] = MFMA16(bf[I][1], b1, acc[1][1]);                    \
    bp += 1024;                                                     \
} while (0)

__global__ void __launch_bounds__(512)
lstm_main(const _Float16* __restrict__ w1p, const _Float16* __restrict__ w0p,
          const _Float16* __restrict__ xh,
          _Float16* __restrict__ bufA, _Float16* __restrict__ bufB,
          float* __restrict__ hbF,
          const float* __restrict__ c0,
          const float* __restrict__ bih0, const float* __restrict__ bhh0,
          const float* __restrict__ bih1, const float* __restrict__ bhh1,
          const float* __restrict__ Wout, const float* __restrict__ bout,
          float* __restrict__ out, unsigned* __restrict__ sync)
{
    __shared__ _Float16 wlds[65536];   // 128 KiB

    const int tid  = threadIdx.x;
    const int lane = tid & 63;
    const int w    = tid >> 6;           // 0..7
    const int bid  = blockIdx.x;
    const int xcd  = bid & 7;
    const int slot = bid >> 3;           // 0..31
    const int isL1 = ((slot & 1) == 0);  // 16 L1 + 16 L0 blocks per XCD
    const int cb   = xcd * 16 + (slot >> 1);   // 0..127 column-block id
    const int cpy  = (slot >> 1) & 1;    // h-copy selector: 16/16 per XCD
    const int jbase = cb * 8;
    const int jj = lane & 15;
    const int kb = lane >> 4;            // 0..3
    const int jh = jj & 7;
    const int lo = (jj < 8);
    const int rowbase = w * 32;          // wave's 32 batch rows

    unsigned* xcdgo = sync + 256 + xcd * 16;   // 64B-separated per-XCD flags

    // ---- load this block's weights into LDS (once) ----
    {
        const _Float16* src = isL1 ? (w1p + (size_t)cb * 65536)
                                   : (w0p + (size_t)cb * 36864);
        const int nch = isL1 ? 8192 : 4608;   // 16B chunks
        for (int i = tid; i < nch; i += 512)
            *(half8*)&wlds[(size_t)i * 8] = *(const half8*)&src[(size_t)i * 8];
    }
    __syncthreads();

    // ---- biases + cell-state init ----
    const float* bi  = isL1 ? bih1 : bih0;
    const float* bhp = isL1 ? bhh1 : bhh0;
    float bias[4];
#pragma unroll
    for (int g = 0; g < 4; ++g)
        bias[g] = bi[g * 1024 + jbase + jh] + bhp[g * 1024 + jbase + jh];

    float cc[2][4];
#pragma unroll
    for (int mf = 0; mf < 2; ++mf)
#pragma unroll
        for (int r = 0; r < 4; ++r)
            cc[mf][r] = c0[(size_t)(rowbase + mf * 16 + kb * 4 + r) * Hq + jbase + jh];

    floatx4 acc[2][2];
    half8 bf[8][2];                      // ring: 8 slots x 2 frags = 64 VGPRs

    for (int t = -1; t <= 255; ++t) {
        const int active = isL1 ? (t >= 0) : (t < 255);
        if (active) {
#pragma unroll
            for (int mf = 0; mf < 2; ++mf)
#pragma unroll
                for (int n = 0; n < 2; ++n)
                    acc[mf][n] = (floatx4){0.f, 0.f, 0.f, 0.f};

            const _Float16* bp = wlds + kb * 256 + jj * 8;

            if (isL1) {
                // gates1(t) = h_a(t)@Wih1^T + h_b(t-1)@Whh1^T  (64 K-steps)
                const _Float16* apA = bufA + ((size_t)(t & 1) * 2 + cpy) * BH
                                    + (size_t)(rowbase + jj) * Hq + kb * 8;
                const _Float16* apB = bufB + ((size_t)((t + 1) & 1) * 2 + cpy) * BH
                                    + (size_t)(rowbase + jj) * Hq + kb * 8;
#define L1P0(S) (((S) < 32) ? (apA + (S) * 32) : (apB + ((S) - 32) * 32))
#define L1P1(S) (L1P0(S) + 16 * Hq)
#pragma unroll
                for (int i = 0; i < 8; ++i) PISSUE(i, L1P0(i), L1P1(i));
#pragma unroll
                for (int s = 0; s < 56; ++s)
                    PSTEP14(s & 7, L1P0(s + 8), L1P1(s + 8));
                PSTEPW(0, 14); PSTEPW(1, 12); PSTEPW(2, 10); PSTEPW(3, 8);
                PSTEPW(4, 6);  PSTEPW(5, 4);  PSTEPW(6, 2);  PSTEPW(7, 0);
#undef L1P0
#undef L1P1
            } else {
                // gates0(t+1) = x(t+1)@Wih0^T + h_a(t)@Whh0^T  (36 K-steps)
                const _Float16* apX = xh + (size_t)(t + 1) * (Bq * 128)
                                    + (size_t)(rowbase + jj) * 128 + kb * 8;
                const _Float16* apA = bufA + ((size_t)(t & 1) * 2 + cpy) * BH
                                    + (size_t)(rowbase + jj) * Hq + kb * 8;
#define L0P0(S) (((S) < 4) ? (apX + (S) * 32) : (apA + ((S) - 4) * 32))
#define L0P1(S) (((S) < 4) ? (L0P0(S) + 16 * 128) : (L0P0(S) + 16 * Hq))
#pragma unroll
                for (int i = 0; i < 8; ++i) PISSUE(i, L0P0(i), L0P1(i));
#pragma unroll
                for (int s = 0; s < 28; ++s)
                    PSTEP14(s & 7, L0P0(s + 8), L0P1(s + 8));
                PSTEPW(4, 14); PSTEPW(5, 12); PSTEPW(6, 10); PSTEPW(7, 8);
                PSTEPW(0, 6);  PSTEPW(1, 4);  PSTEPW(2, 2);  PSTEPW(3, 0);
#undef L0P0
#undef L0P1
            }

            // ---- elementwise: gate-pair exchange + cell update + h store ----
            // h stores: fp16 pairs packed to 4B words, RELAXED agent atomics,
            // written to BOTH copies of the destination parity.
            _Float16* hb = isL1 ? (bufB + (size_t)(t & 1) * 2 * BH)
                                : (bufA + (size_t)((t + 1) & 1) * 2 * BH);
            unsigned* hb32 = (unsigned*)hb;
#pragma unroll
            for (int mf = 0; mf < 2; ++mf) {
#pragma unroll
                for (int r = 0; r < 4; ++r) {
                    float o0 = acc[mf][0][r];       // lo: i, hi: f
                    float o1 = acc[mf][1][r];       // lo: g, hi: o
                    float p0 = __shfl_xor(o0, 8);
                    float p1 = __shfl_xor(o1, 8);
                    float gi = (lo ? o0 : p0) + bias[0];
                    float gf = (lo ? p0 : o0) + bias[1];
                    float gg = (lo ? o1 : p1) + bias[2];
                    float go = (lo ? p1 : o1) + bias[3];
                    float ii = 1.f / (1.f + expf(-gi));
                    float ff = 1.f / (1.f + expf(-gf));
                    float gt = tanhf(gg);
                    float oo = 1.f / (1.f + expf(-go));
                    float cn = ff * cc[mf][r] + ii * gt;
                    cc[mf][r] = cn;
                    float hn = oo * tanhf(cn);

                    union { _Float16 f; unsigned short u; } cv;
                    cv.f = (_Float16)hn;
                    int prt = __shfl_xor((int)cv.u, 1);   // neighbor j^1's bits
                    int row = rowbase + mf * 16 + kb * 4 + r;
                    if (lo && ((jh & 1) == 0)) {
                        unsigned word = (unsigned)cv.u | ((unsigned)prt << 16);
                        size_t widx = ((size_t)row * Hq + jbase + jh) >> 1;
                        __hip_atomic_store(hb32 + widx, word, __ATOMIC_RELAXED,
                                           __HIP_MEMORY_SCOPE_AGENT);
                        __hip_atomic_store(hb32 + widx + (BH >> 1), word,
                                           __ATOMIC_RELAXED,
                                           __HIP_MEMORY_SCOPE_AGENT);
                    }
                    if (lo && isL1 && t == 255)
                        __hip_atomic_store(hbF + (size_t)row * Hq + jbase + jh,
                                           hn, __ATOMIC_RELAXED,
                                           __HIP_MEMORY_SCOPE_AGENT);
                }
            }
        }

        gridbar(sync, bid, (unsigned)(t + 2));
        invround(xcdgo, slot, (unsigned)(t + 2));
    }

    // ---- final: out[b][o] = b_out[o] + sum_k hbF[b][k] * Wout[o][k] ----
    // (t=255 invround already freshened L2/L1 for hbF's cached reads)
    int gid = bid * 512 + tid;
    if (gid < Bq * 128) {
        int b = gid >> 7, o = gid & 127;
        const floatx4* hr = (const floatx4*)(hbF + (size_t)b * Hq);
        const floatx4* wr = (const floatx4*)(Wout + (size_t)o * Hq);
        float s = bout[o];
#pragma unroll 4
        for (int k = 0; k < Hq / 4; ++k) {
            floatx4 hv = hr[k], wv = wr[k];
            s += hv[0] * wv[0] + hv[1] * wv[1] + hv[2] * wv[2] + hv[3] * wv[3];
        }
        out[gid] = s;
    }
}

// ---------------------------------------------------------------------------
extern "C" void kernel_launch(void* const* d_in, const int* in_sizes, int n_in,
                              void* d_out, int out_size, void* d_ws, size_t ws_size,
                              hipStream_t stream)
{
    (void)in_sizes; (void)n_in;
    float* out = (float*)d_out;

    if (ws_size < (size_t)REQ_WS) {
        float v = -(float)(ws_size >> 20);
        hipLaunchKernelGGL(ws_sentinel_kernel, dim3((out_size + 255) / 256), dim3(256),
                           0, stream, out, out_size, v);
        return;
    }

    const float* x    = (const float*)d_in[0];
    const float* h0   = (const float*)d_in[1];
    const float* c0   = (const float*)d_in[2];
    const float* Wih0 = (const float*)d_in[3];
    const float* Whh0 = (const float*)d_in[4];
    const float* bih0 = (const float*)d_in[5];
    const float* bhh0 = (const float*)d_in[6];
    const float* Wih1 = (const float*)d_in[7];
    const float* Whh1 = (const float*)d_in[8];
    const float* bih1 = (const float*)d_in[9];
    const float* bhh1 = (const float*)d_in[10];
    const float* Wout = (const float*)d_in[11];
    const float* bout = (const float*)d_in[12];

    char* ws = (char*)d_ws;
    _Float16* w1p  = (_Float16*)(ws + OFF_W1);
    _Float16* w0p  = (_Float16*)(ws + OFF_W0);
    _Float16* xh   = (_Float16*)(ws + OFF_XH);
    _Float16* bufA = (_Float16*)(ws + OFF_BA);
    _Float16* bufB = (_Float16*)(ws + OFF_BB);
    float*    hbF  = (float*)   (ws + OFF_HF);
    unsigned* sync = (unsigned*)(ws + OFF_SY);

    long long total = N_W1 + N_W0 + N_XH + N_H;   // 21,757,952 = 84992*256
    hipLaunchKernelGGL(prep_kernel, dim3((unsigned)(total / 256)), dim3(256), 0, stream,
                       x, h0, Wih0, Whh0, Wih1, Whh1, w1p, w0p, xh, bufA, bufB, sync);

    hipLaunchKernelGGL(lstm_main, dim3(256), dim3(512), 0, stream,
                       w1p, w0p, xh, bufA, bufB, hbF, c0,
                       bih0, bhh0, bih1, bhh1, Wout, bout, out, sync);
}

// Round 22
// 5845.161 us; speedup vs baseline: 3.8060x; 1.6269x over previous
//
#include <hip/hip_runtime.h>
#include <hip/hip_fp16.h>

// ---------------------------------------------------------------------------
// 2-layer LSTM (B=256, T=256, D=128, H=1024) + final Linear(H->128).
// Persistent kernel, one phase per timestep, flag-array grid barrier +
// single-L2-inv-per-XCD (R15/R18). K-loop = R13 asm ring-8 pipeline.
//
// R22: COALESCED TILED h/x LAYOUT. Old layout: lane jj read row rowbase+jj
// at 2KB stride -> each wave load touched 16 half-used lines; 16-deep ring
// x 16 lines = far beyond L1 miss-tracking -> ~2-4 effective loads in
// flight (why R13's ring was a no-op; R19's coalesced spills flew at
// 1.5TB/s). New layout h[parity][ks-tile][row][32] (k = ks*32+kb*8+e
// unchanged -> same weights, same math): each wave load = 1KB contiguous,
// 8 dense lines. Sequential ks sweep preserved (R20 lesson).
// ---------------------------------------------------------------------------

#define Bq 256
#define Hq 1024

typedef _Float16 half8 __attribute__((ext_vector_type(8)));
typedef float    floatx4 __attribute__((ext_vector_type(4)));

#define N_W1 8388608LL   // 128 cb * 65536  ([ks64][kb4][n2][jj16][e8])
#define N_W0 4718592LL   // 128 cb * 36864  ([ks36][kb4][n2][jj16][e8])
#define N_XH 8388608LL   // T*B*D  (tiled: [t][4][256][32])
#define N_H  262144LL    // B*H
#define BH   262144

// ws byte offsets
#define OFF_W1 0LL
#define OFF_W0 16777216LL
#define OFF_XH 26214400LL
#define OFF_BA 42991616LL
#define OFF_BB 44040192LL
#define OFF_HF 45088768LL
#define OFF_SY 46137344LL
#define REQ_WS 46139392LL   // OFF_SY + 2048

// ---------------------------------------------------------------------------
__global__ void ws_sentinel_kernel(float* __restrict__ out, int n, float v)
{
    int i = blockIdx.x * blockDim.x + threadIdx.x;
    if (i < n) out[i] = v;
}

// ---------------------------------------------------------------------------
__global__ void prep_kernel(const float* __restrict__ x, const float* __restrict__ h0,
                            const float* __restrict__ Wih0, const float* __restrict__ Whh0,
                            const float* __restrict__ Wih1, const float* __restrict__ Whh1,
                            _Float16* __restrict__ w1p, _Float16* __restrict__ w0p,
                            _Float16* __restrict__ xh,
                            _Float16* __restrict__ bufA, _Float16* __restrict__ bufB,
                            unsigned* __restrict__ sync)
{
    long long gid = (long long)blockIdx.x * blockDim.x + threadIdx.x;
    if (gid < 512) sync[gid] = 0u;   // [0..255] global flags, [256..511] xcdgo

    if (gid < N_W1) {
        // [cb][ks][kb][n][jj][e]; gate-col row = (2n + jj>>3)*1024 + cb*8 + (jj&7)
        long long i = gid;
        int e  = (int)(i & 7);
        int jj = (int)((i >> 3) & 15);
        int n  = (int)((i >> 7) & 1);
        int kb = (int)((i >> 8) & 3);
        int ks = (int)((i >> 10) & 63);
        int cb = (int)(i >> 16);
        int row = (2 * n + (jj >> 3)) * 1024 + cb * 8 + (jj & 7);
        int k = ks * 32 + kb * 8 + e;
        float v = (k < 1024) ? Wih1[(size_t)row * 1024 + k]
                             : Whh1[(size_t)row * 1024 + (k - 1024)];
        w1p[i] = (_Float16)v;
    } else if (gid < N_W1 + N_W0) {
        long long i = gid - N_W1;
        int cb = (int)(i / 36864LL);
        int r  = (int)(i - (long long)cb * 36864LL);
        int ks = r >> 10;
        int kb = (r >> 8) & 3;
        int n  = (r >> 7) & 1;
        int jj = (r >> 3) & 15;
        int e  = r & 7;
        int row = (2 * n + (jj >> 3)) * 1024 + cb * 8 + (jj & 7);
        int k = ks * 32 + kb * 8 + e;
        float v = (k < 128) ? Wih0[(size_t)row * 128 + k]
                            : Whh0[(size_t)row * 1024 + (k - 128)];
        w0p[i] = (_Float16)v;
    } else if (gid < N_W1 + N_W0 + N_XH) {
        long long i = gid - N_W1 - N_W0;
        // xh tiled: [t][tile4][b][32]; element d = tile*32+e of x[b][t][:]
        int t    = (int)(i >> 15);
        int rem  = (int)(i & 32767);
        int tile = rem >> 13;
        int b    = (rem >> 5) & 255;
        int e    = rem & 31;
        int d    = tile * 32 + e;
        xh[i] = (_Float16)x[((size_t)b * 256 + t) * 128 + d];
    } else if (gid < N_W1 + N_W0 + N_XH + N_H) {
        long long i = gid - N_W1 - N_W0 - N_XH;
        // h0 is [row][H]; tiled dest idx = (j>>5)*8192 + row*32 + (j&31)
        int row = (int)(i >> 10);
        int j   = (int)(i & 1023);
        size_t idx = (size_t)(j >> 5) * 8192 + (size_t)row * 32 + (j & 31);
        _Float16 v = (_Float16)h0[i];
        bufA[BH + idx] = v;   // h_a(-1) parity 1
        bufB[BH + idx] = v;   // h_b(-1) parity 1
    }
}

// ---------------------------------------------------------------------------
// Global flag-array barrier, fence-free (freshness handled by invround).
__device__ __forceinline__ void gridbar(unsigned* flags, int bid, unsigned target)
{
    __builtin_amdgcn_s_waitcnt(0);     // own write-through stores at IF
    __syncthreads();
    if (threadIdx.x == 0)
        __hip_atomic_store(flags + bid, target, __ATOMIC_RELAXED,
                           __HIP_MEMORY_SCOPE_AGENT);
    if (threadIdx.x < 256) {
        int guard = 0;
        while (__hip_atomic_load(flags + threadIdx.x, __ATOMIC_RELAXED,
                                 __HIP_MEMORY_SCOPE_AGENT) < target) {
            __builtin_amdgcn_s_sleep(1);
            if (++guard > (1 << 18)) break;        // safety: wrong, not wedged
        }
    }
    __syncthreads();
}

// ---------------------------------------------------------------------------
// Per-XCD single-L2-invalidate round (R15/R18 protocol, unchanged).
__device__ __forceinline__ void invround(unsigned* xcdgo, int slot, unsigned target)
{
    if (slot == 0) {
        if (threadIdx.x < 64) {
            __builtin_amdgcn_fence(__ATOMIC_ACQUIRE, "agent");   // buffer_inv sc1
            asm volatile("s_waitcnt vmcnt(0) lgkmcnt(0)" ::: "memory");
            if (threadIdx.x == 0)
                __hip_atomic_store(xcdgo, target, __ATOMIC_RELAXED,
                                   __HIP_MEMORY_SCOPE_AGENT);
        }
        __syncthreads();      // whole block (same CU) now fresh
    } else {
        if (threadIdx.x == 0) {
            int guard = 0;
            while (__hip_atomic_load(xcdgo, __ATOMIC_RELAXED,
                                     __HIP_MEMORY_SCOPE_AGENT) < target) {
                __builtin_amdgcn_s_sleep(1);
                if (++guard > (1 << 18)) break;
            }
        }
        __syncthreads();      // all waves gated until L2 is clean
        if (threadIdx.x == 0) {
            asm volatile("buffer_inv" ::: "memory");             // L1-only
            asm volatile("s_waitcnt vmcnt(0)" ::: "memory");
        }
        __syncthreads();
    }
}

#define MFMA16(A, Bv, C) __builtin_amdgcn_mfma_f32_16x16x32_f16((A), (Bv), (C), 0, 0, 0)

// ---- inline-asm pipelined K-step machinery (R13, unchanged) ---------------
#define PISSUE(I, P0, P1)                                           \
    asm volatile("global_load_dwordx4 %0, %2, off\n\t"              \
                 "global_load_dwordx4 %1, %3, off"                  \
                 : "=&v"(bf[I][0]), "=&v"(bf[I][1])                 \
                 : "v"(P0), "v"(P1) : "memory")

#define PSTEP14(I, P0, P1) do {                                     \
    half8 b0 = *(const half8*)(bp);                                 \
    half8 b1 = *(const half8*)(bp + 128);                           \
    asm volatile("s_waitcnt vmcnt(14)" ::: "memory");               \
    __builtin_amdgcn_sched_barrier(0);                              \
    acc[0][0] = MFMA16(bf[I][0], b0, acc[0][0]);                    \
    acc[0][1] = MFMA16(bf[I][0], b1, acc[0][1]);                    \
    acc[1][0] = MFMA16(bf[I][1], b0, acc[1][0]);                    \
    acc[1][1] = MFMA16(bf[I][1], b1, acc[1][1]);                    \
    bp += 1024;                                                     \
    PISSUE(I, P0, P1);                                              \
} while (0)

#define PSTEPW(I, NLIT) do {                                        \
    half8 b0 = *(const half8*)(bp);                                 \
    half8 b1 = *(const half8*)(bp + 128);                           \
    asm volatile("s_waitcnt vmcnt(" #NLIT ")" ::: "memory");        \
    __builtin_amdgcn_sched_barrier(0);                              \
    acc[0][0] = MFMA16(bf[I][0], b0, acc[0][0]);                    \
    acc[0][1] = MFMA16(bf[I][0], b1, acc[0][1]);                    \
    acc[1][0] = MFMA16(bf[I][1], b0, acc[1][0]);                    \
    acc[1][1] = MFMA16(bf[I][1], b1, acc[1][1]);                    \
    bp += 1024;                                                     \
} while (0)

__global__ void __launch_bounds__(512)
lstm_main(const _Float16* __restrict__ w1p, const _Float16* __restrict__ w0p,
          const _Float16* __restrict__ xh,
          _Float16* __restrict__ bufA, _Float16* __restrict__ bufB,
          float* __restrict__ hbF,
          const float* __restrict__ c0,
          const float* __restrict__ bih0, const float* __restrict__ bhh0,
          const float* __restrict__ bih1, const float* __restrict__ bhh1,
          const float* __restrict__ Wout, const float* __restrict__ bout,
          float* __restrict__ out, unsigned* __restrict__ sync)
{
    __shared__ _Float16 wlds[65536];   // 128 KiB

    const int tid  = threadIdx.x;
    const int lane = tid & 63;
    const int w    = tid >> 6;           // 0..7
    const int bid  = blockIdx.x;
    const int xcd  = bid & 7;
    const int slot = bid >> 3;           // 0..31
    const int isL1 = ((slot & 1) == 0);  // 16 L1 + 16 L0 blocks per XCD
    const int cb   = xcd * 16 + (slot >> 1);   // 0..127 column-block id
    const int jbase = cb * 8;
    const int jj = lane & 15;
    const int kb = lane >> 4;            // 0..3
    const int jh = jj & 7;
    const int lo = (jj < 8);
    const int rowbase = w * 32;          // wave's 32 batch rows

    unsigned* xcdgo = sync + 256 + xcd * 16;   // 64B-separated per-XCD flags

    // tiled h-store column index: j = jbase + jh -> tile cb>>2, col (cb&3)*8+jh
    const int jtile = cb >> 2;
    const int jcol  = (cb & 3) * 8 + jh;

    // ---- load this block's weights into LDS (once) ----
    {
        const _Float16* src = isL1 ? (w1p + (size_t)cb * 65536)
                                   : (w0p + (size_t)cb * 36864);
        const int nch = isL1 ? 8192 : 4608;   // 16B chunks
        for (int i = tid; i < nch; i += 512)
            *(half8*)&wlds[(size_t)i * 8] = *(const half8*)&src[(size_t)i * 8];
    }
    __syncthreads();

    // ---- biases + cell-state init ----
    const float* bi  = isL1 ? bih1 : bih0;
    const float* bhp = isL1 ? bhh1 : bhh0;
    float bias[4];
#pragma unroll
    for (int g = 0; g < 4; ++g)
        bias[g] = bi[g * 1024 + jbase + jh] + bhp[g * 1024 + jbase + jh];

    float cc[2][4];
#pragma unroll
    for (int mf = 0; mf < 2; ++mf)
#pragma unroll
        for (int r = 0; r < 4; ++r)
            cc[mf][r] = c0[(size_t)(rowbase + mf * 16 + kb * 4 + r) * Hq + jbase + jh];

    floatx4 acc[2][2];
    half8 bf[8][2];                      // ring: 8 slots x 2 frags = 64 VGPRs

    for (int t = -1; t <= 255; ++t) {
        const int active = isL1 ? (t >= 0) : (t < 255);
        if (active) {
#pragma unroll
            for (int mf = 0; mf < 2; ++mf)
#pragma unroll
                for (int n = 0; n < 2; ++n)
                    acc[mf][n] = (floatx4){0.f, 0.f, 0.f, 0.f};

            const _Float16* bp = wlds + kb * 256 + jj * 8;
            // per-lane tiled offset: (rowbase+jj)*32 + kb*8 -> 1KB/wave load
            const size_t loff = (size_t)(rowbase + jj) * 32 + kb * 8;

            if (isL1) {
                // gates1(t) = h_a(t)@Wih1^T + h_b(t-1)@Whh1^T  (64 K-steps)
                const _Float16* apA = bufA + (size_t)(t & 1) * BH + loff;
                const _Float16* apB = bufB + (size_t)((t + 1) & 1) * BH + loff;
#define L1P0(S) (((S) < 32) ? (apA + (size_t)(S) * 8192) : (apB + (size_t)((S) - 32) * 8192))
#define L1P1(S) (L1P0(S) + 512)
#pragma unroll
                for (int i = 0; i < 8; ++i) PISSUE(i, L1P0(i), L1P1(i));
#pragma unroll
                for (int s = 0; s < 56; ++s)
                    PSTEP14(s & 7, L1P0(s + 8), L1P1(s + 8));
                PSTEPW(0, 14); PSTEPW(1, 12); PSTEPW(2, 10); PSTEPW(3, 8);
                PSTEPW(4, 6);  PSTEPW(5, 4);  PSTEPW(6, 2);  PSTEPW(7, 0);
#undef L1P0
#undef L1P1
            } else {
                // gates0(t+1) = x(t+1)@Wih0^T + h_a(t)@Whh0^T  (36 K-steps)
                const _Float16* apX = xh + (size_t)(t + 1) * 32768 + loff;
                const _Float16* apA = bufA + (size_t)(t & 1) * BH + loff;
#define L0P0(S) (((S) < 4) ? (apX + (size_t)(S) * 8192) : (apA + (size_t)((S) - 4) * 8192))
#define L0P1(S) (L0P0(S) + 512)
#pragma unroll
                for (int i = 0; i < 8; ++i) PISSUE(i, L0P0(i), L0P1(i));
#pragma unroll
                for (int s = 0; s < 28; ++s)
                    PSTEP14(s & 7, L0P0(s + 8), L0P1(s + 8));
                PSTEPW(4, 14); PSTEPW(5, 12); PSTEPW(6, 10); PSTEPW(7, 8);
                PSTEPW(0, 6);  PSTEPW(1, 4);  PSTEPW(2, 2);  PSTEPW(3, 0);
#undef L0P0
#undef L0P1
            }

            // ---- elementwise: gate-pair exchange + cell update + h store ----
            // tiled h store: eidx = jtile*8192 + row*32 + jcol (jcol even lane)
            _Float16* hb = isL1 ? (bufB + (size_t)(t & 1) * BH)
                                : (bufA + (size_t)((t + 1) & 1) * BH);
            unsigned* hb32 = (unsigned*)hb;
#pragma unroll
            for (int mf = 0; mf < 2; ++mf) {
#pragma unroll
                for (int r = 0; r < 4; ++r) {
                    float o0 = acc[mf][0][r];       // lo: i, hi: f
                    float o1 = acc[mf][1][r];       // lo: g, hi: o
                    float p0 = __shfl_xor(o0, 8);
                    float p1 = __shfl_xor(o1, 8);
                    float gi = (lo ? o0 : p0) + bias[0];
                    float gf = (lo ? p0 : o0) + bias[1];
                    float gg = (lo ? o1 : p1) + bias[2];
                    float go = (lo ? p1 : o1) + bias[3];
                    float ii = 1.f / (1.f + expf(-gi));
                    float ff = 1.f / (1.f + expf(-gf));
                    float gt = tanhf(gg);
                    float oo = 1.f / (1.f + expf(-go));
                    float cn = ff * cc[mf][r] + ii * gt;
                    cc[mf][r] = cn;
                    float hn = oo * tanhf(cn);

                    union { _Float16 f; unsigned short u; } cv;
                    cv.f = (_Float16)hn;
                    int prt = __shfl_xor((int)cv.u, 1);   // neighbor j^1's bits
                    int row = rowbase + mf * 16 + kb * 4 + r;
                    if (lo && ((jh & 1) == 0)) {
                        unsigned word = (unsigned)cv.u | ((unsigned)prt << 16);
                        size_t eidx = (size_t)jtile * 8192 + (size_t)row * 32 + jcol;
                        __hip_atomic_store(hb32 + (eidx >> 1), word,
                                           __ATOMIC_RELAXED,
                                           __HIP_MEMORY_SCOPE_AGENT);
                    }
                    if (lo && isL1 && t == 255)
                        __hip_atomic_store(hbF + (size_t)row * Hq + jbase + jh,
                                           hn, __ATOMIC_RELAXED,
                                           __HIP_MEMORY_SCOPE_AGENT);
                }
            }
        }

        gridbar(sync, bid, (unsigned)(t + 2));
        invround(xcdgo, slot, (unsigned)(t + 2));
    }

    // ---- final: out[b][o] = b_out[o] + sum_k hbF[b][k] * Wout[o][k] ----
    // (t=255 invround already freshened L2/L1 for hbF's cached reads)
    int gid = bid * 512 + tid;
    if (gid < Bq * 128) {
        int b = gid >> 7, o = gid & 127;
        const floatx4* hr = (const floatx4*)(hbF + (size_t)b * Hq);
        const floatx4* wr = (const floatx4*)(Wout + (size_t)o * Hq);
        float s = bout[o];
#pragma unroll 4
        for (int k = 0; k < Hq / 4; ++k) {
            floatx4 hv = hr[k], wv = wr[k];
            s += hv[0] * wv[0] + hv[1] * wv[1] + hv[2] * wv[2] + hv[3] * wv[3];
        }
        out[gid] = s;
    }
}

// ---------------------------------------------------------------------------
extern "C" void kernel_launch(void* const* d_in, const int* in_sizes, int n_in,
                              void* d_out, int out_size, void* d_ws, size_t ws_size,
                              hipStream_t stream)
{
    (void)in_sizes; (void)n_in;
    float* out = (float*)d_out;

    if (ws_size < (size_t)REQ_WS) {
        float v = -(float)(ws_size >> 20);
        hipLaunchKernelGGL(ws_sentinel_kernel, dim3((out_size + 255) / 256), dim3(256),
                           0, stream, out, out_size, v);
        return;
    }

    const float* x    = (const float*)d_in[0];
    const float* h0   = (const float*)d_in[1];
    const float* c0   = (const float*)d_in[2];
    const float* Wih0 = (const float*)d_in[3];
    const float* Whh0 = (const float*)d_in[4];
    const float* bih0 = (const float*)d_in[5];
    const float* bhh0 = (const float*)d_in[6];
    const float* Wih1 = (const float*)d_in[7];
    const float* Whh1 = (const float*)d_in[8];
    const float* bih1 = (const float*)d_in[9];
    const float* bhh1 = (const float*)d_in[10];
    const float* Wout = (const float*)d_in[11];
    const float* bout = (const float*)d_in[12];

    char* ws = (char*)d_ws;
    _Float16* w1p  = (_Float16*)(ws + OFF_W1);
    _Float16* w0p  = (_Float16*)(ws + OFF_W0);
    _Float16* xh   = (_Float16*)(ws + OFF_XH);
    _Float16* bufA = (_Float16*)(ws + OFF_BA);
    _Float16* bufB = (_Float16*)(ws + OFF_BB);
    float*    hbF  = (float*)   (ws + OFF_HF);
    unsigned* sync = (unsigned*)(ws + OFF_SY);

    long long total = N_W1 + N_W0 + N_XH + N_H;   // 21,757,952 = 84992*256
    hipLaunchKernelGGL(prep_kernel, dim3((unsigned)(total / 256)), dim3(256), 0, stream,
                       x, h0, Wih0, Whh0, Wih1, Whh1, w1p, w0p, xh, bufA, bufB, sync);

    hipLaunchKernelGGL(lstm_main, dim3(256), dim3(512), 0, stream,
                       w1p, w0p, xh, bufA, bufB, hbF, c0,
                       bih0, bhh0, bih1, bhh1, Wout, bout, out, sync);
}

// Round 23
// 5232.755 us; speedup vs baseline: 4.2515x; 1.1170x over previous
//
#include <hip/hip_runtime.h>
#include <hip/hip_fp16.h>

// ---------------------------------------------------------------------------
// 2-layer LSTM (B=256, T=256, D=128, H=1024) + final Linear(H->128).
// Persistent kernel, one phase per timestep. fp16 MFMA, fp32 accum.
// Weights in LDS; h/x in COALESCED TILED layout (R22: 1KB dense wave-loads).
//
// R23: (1) ring-8 -> ring-12 asm pipeline (vmcnt(22), 24 loads in flight
// per wave) to cover IF first-touch latency after the per-phase L2 inv;
// (2) merged phase barrier: non-slot0 blocks wait ONLY on xcdgo (slot-0
// polls the 256 arrival flags, does the single L2+L1 fence, publishes) --
// removes one IF polling round-trip for 31/32 blocks.
// ---------------------------------------------------------------------------

#define Bq 256
#define Hq 1024

typedef _Float16 half8 __attribute__((ext_vector_type(8)));
typedef float    floatx4 __attribute__((ext_vector_type(4)));

#define N_W1 8388608LL   // 128 cb * 65536  ([ks64][kb4][n2][jj16][e8])
#define N_W0 4718592LL   // 128 cb * 36864  ([ks36][kb4][n2][jj16][e8])
#define N_XH 8388608LL   // T*B*D  (tiled: [t][4][256][32])
#define N_H  262144LL    // B*H
#define BH   262144

// ws byte offsets
#define OFF_W1 0LL
#define OFF_W0 16777216LL
#define OFF_XH 26214400LL
#define OFF_BA 42991616LL
#define OFF_BB 44040192LL
#define OFF_HF 45088768LL
#define OFF_SY 46137344LL
#define REQ_WS 46139392LL   // OFF_SY + 2048

// ---------------------------------------------------------------------------
__global__ void ws_sentinel_kernel(float* __restrict__ out, int n, float v)
{
    int i = blockIdx.x * blockDim.x + threadIdx.x;
    if (i < n) out[i] = v;
}

// ---------------------------------------------------------------------------
__global__ void prep_kernel(const float* __restrict__ x, const float* __restrict__ h0,
                            const float* __restrict__ Wih0, const float* __restrict__ Whh0,
                            const float* __restrict__ Wih1, const float* __restrict__ Whh1,
                            _Float16* __restrict__ w1p, _Float16* __restrict__ w0p,
                            _Float16* __restrict__ xh,
                            _Float16* __restrict__ bufA, _Float16* __restrict__ bufB,
                            unsigned* __restrict__ sync)
{
    long long gid = (long long)blockIdx.x * blockDim.x + threadIdx.x;
    if (gid < 512) sync[gid] = 0u;   // [0..255] global flags, [256..511] xcdgo

    if (gid < N_W1) {
        // [cb][ks][kb][n][jj][e]; gate-col row = (2n + jj>>3)*1024 + cb*8 + (jj&7)
        long long i = gid;
        int e  = (int)(i & 7);
        int jj = (int)((i >> 3) & 15);
        int n  = (int)((i >> 7) & 1);
        int kb = (int)((i >> 8) & 3);
        int ks = (int)((i >> 10) & 63);
        int cb = (int)(i >> 16);
        int row = (2 * n + (jj >> 3)) * 1024 + cb * 8 + (jj & 7);
        int k = ks * 32 + kb * 8 + e;
        float v = (k < 1024) ? Wih1[(size_t)row * 1024 + k]
                             : Whh1[(size_t)row * 1024 + (k - 1024)];
        w1p[i] = (_Float16)v;
    } else if (gid < N_W1 + N_W0) {
        long long i = gid - N_W1;
        int cb = (int)(i / 36864LL);
        int r  = (int)(i - (long long)cb * 36864LL);
        int ks = r >> 10;
        int kb = (r >> 8) & 3;
        int n  = (r >> 7) & 1;
        int jj = (r >> 3) & 15;
        int e  = r & 7;
        int row = (2 * n + (jj >> 3)) * 1024 + cb * 8 + (jj & 7);
        int k = ks * 32 + kb * 8 + e;
        float v = (k < 128) ? Wih0[(size_t)row * 128 + k]
                            : Whh0[(size_t)row * 1024 + (k - 128)];
        w0p[i] = (_Float16)v;
    } else if (gid < N_W1 + N_W0 + N_XH) {
        long long i = gid - N_W1 - N_W0;
        // xh tiled: [t][tile4][b][32]; element d = tile*32+e of x[b][t][:]
        int t    = (int)(i >> 15);
        int rem  = (int)(i & 32767);
        int tile = rem >> 13;
        int b    = (rem >> 5) & 255;
        int e    = rem & 31;
        int d    = tile * 32 + e;
        xh[i] = (_Float16)x[((size_t)b * 256 + t) * 128 + d];
    } else if (gid < N_W1 + N_W0 + N_XH + N_H) {
        long long i = gid - N_W1 - N_W0 - N_XH;
        // h0 is [row][H]; tiled dest idx = (j>>5)*8192 + row*32 + (j&31)
        int row = (int)(i >> 10);
        int j   = (int)(i & 1023);
        size_t idx = (size_t)(j >> 5) * 8192 + (size_t)row * 32 + (j & 31);
        _Float16 v = (_Float16)h0[i];
        bufA[BH + idx] = v;   // h_a(-1) parity 1
        bufB[BH + idx] = v;   // h_b(-1) parity 1
    }
}

// ---------------------------------------------------------------------------
// Merged phase barrier + single-L2-inv-per-XCD.
//  all blocks: drain stores, publish flags[bid]
//  slot-0:     poll 256 flags -> agent fence (L2+L1 inv) -> publish xcdgo
//  others:     poll xcdgo only -> L1-only buffer_inv
__device__ __forceinline__ void phasebar(unsigned* flags, unsigned* xcdgo,
                                         int bid, int slot, unsigned target)
{
    __builtin_amdgcn_s_waitcnt(0);     // own write-through stores at IF
    __syncthreads();
    if (threadIdx.x == 0)
        __hip_atomic_store(flags + bid, target, __ATOMIC_RELAXED,
                           __HIP_MEMORY_SCOPE_AGENT);
    if (slot == 0) {
        if (threadIdx.x < 256) {
            int guard = 0;
            while (__hip_atomic_load(flags + threadIdx.x, __ATOMIC_RELAXED,
                                     __HIP_MEMORY_SCOPE_AGENT) < target) {
                __builtin_amdgcn_s_sleep(1);
                if (++guard > (1 << 18)) break;    // safety: wrong, not wedged
            }
        }
        __syncthreads();
        if (threadIdx.x < 64) {
            __builtin_amdgcn_fence(__ATOMIC_ACQUIRE, "agent");   // L2+L1 inv
            asm volatile("s_waitcnt vmcnt(0) lgkmcnt(0)" ::: "memory");
            if (threadIdx.x == 0)
                __hip_atomic_store(xcdgo, target, __ATOMIC_RELAXED,
                                   __HIP_MEMORY_SCOPE_AGENT);
        }
        __syncthreads();
    } else {
        if (threadIdx.x == 0) {
            int guard = 0;
            while (__hip_atomic_load(xcdgo, __ATOMIC_RELAXED,
                                     __HIP_MEMORY_SCOPE_AGENT) < target) {
                __builtin_amdgcn_s_sleep(1);
                if (++guard > (1 << 18)) break;
            }
        }
        __syncthreads();      // all waves gated until L2 is clean
        if (threadIdx.x == 0) {
            asm volatile("buffer_inv" ::: "memory");             // L1-only
            asm volatile("s_waitcnt vmcnt(0)" ::: "memory");
        }
        __syncthreads();
    }
}

#define MFMA16(A, Bv, C) __builtin_amdgcn_mfma_f32_16x16x32_f16((A), (Bv), (C), 0, 0, 0)

// ---- inline-asm ring-12 pipelined K-step machinery ------------------------
#define PISSUE(I, P0, P1)                                           \
    asm volatile("global_load_dwordx4 %0, %2, off\n\t"              \
                 "global_load_dwordx4 %1, %3, off"                  \
                 : "=&v"(bf[I][0]), "=&v"(bf[I][1])                 \
                 : "v"(P0), "v"(P1) : "memory")

#define PSTEP22(I, P0, P1) do {                                     \
    half8 b0 = *(const half8*)(bp);                                 \
    half8 b1 = *(const half8*)(bp + 128);                           \
    asm volatile("s_waitcnt vmcnt(22)" ::: "memory");               \
    __builtin_amdgcn_sched_barrier(0);                              \
    acc[0][0] = MFMA16(bf[I][0], b0, acc[0][0]);                    \
    acc[0][1] = MFMA16(bf[I][0], b1, acc[0][1]);                    \
    acc[1][0] = MFMA16(bf[I][1], b0, acc[1][0]);                    \
    acc[1][1] = MFMA16(bf[I][1], b1, acc[1][1]);                    \
    bp += 1024;                                                     \
    PISSUE(I, P0, P1);                                              \
} while (0)

#define PSTEPW(I, NLIT) do {                                        \
    half8 b0 = *(const half8*)(bp);                                 \
    half8 b1 = *(const half8*)(bp + 128);                           \
    asm volatile("s_waitcnt vmcnt(" #NLIT ")" ::: "memory");        \
    __builtin_amdgcn_sched_barrier(0);                              \
    acc[0][0] = MFMA16(bf[I][0], b0, acc[0][0]);                    \
    acc[0][1] = MFMA16(bf[I][0], b1, acc[0][1]);                    \
    acc[1][0] = MFMA16(bf[I][1], b0, acc[1][0]);                    \
    acc[1][1] = MFMA16(bf[I][1], b1, acc[1][1]);                    \
    bp += 1024;                                                     \
} while (0)

__global__ void __launch_bounds__(512)
lstm_main(const _Float16* __restrict__ w1p, const _Float16* __restrict__ w0p,
          const _Float16* __restrict__ xh,
          _Float16* __restrict__ bufA, _Float16* __restrict__ bufB,
          float* __restrict__ hbF,
          const float* __restrict__ c0,
          const float* __restrict__ bih0, const float* __restrict__ bhh0,
          const float* __restrict__ bih1, const float* __restrict__ bhh1,
          const float* __restrict__ Wout, const float* __restrict__ bout,
          float* __restrict__ out, unsigned* __restrict__ sync)
{
    __shared__ _Float16 wlds[65536];   // 128 KiB

    const int tid  = threadIdx.x;
    const int lane = tid & 63;
    const int w    = tid >> 6;           // 0..7
    const int bid  = blockIdx.x;
    const int xcd  = bid & 7;
    const int slot = bid >> 3;           // 0..31
    const int isL1 = ((slot & 1) == 0);  // 16 L1 + 16 L0 blocks per XCD
    const int cb   = xcd * 16 + (slot >> 1);   // 0..127 column-block id
    const int jbase = cb * 8;
    const int jj = lane & 15;
    const int kb = lane >> 4;            // 0..3
    const int jh = jj & 7;
    const int lo = (jj < 8);
    const int rowbase = w * 32;          // wave's 32 batch rows

    unsigned* xcdgo = sync + 256 + xcd * 16;   // 64B-separated per-XCD flags

    // tiled h-store column index: j = jbase + jh -> tile cb>>2, col (cb&3)*8+jh
    const int jtile = cb >> 2;
    const int jcol  = (cb & 3) * 8 + jh;

    // ---- load this block's weights into LDS (once) ----
    {
        const _Float16* src = isL1 ? (w1p + (size_t)cb * 65536)
                                   : (w0p + (size_t)cb * 36864);
        const int nch = isL1 ? 8192 : 4608;   // 16B chunks
        for (int i = tid; i < nch; i += 512)
            *(half8*)&wlds[(size_t)i * 8] = *(const half8*)&src[(size_t)i * 8];
    }
    __syncthreads();

    // ---- biases + cell-state init ----
    const float* bi  = isL1 ? bih1 : bih0;
    const float* bhp = isL1 ? bhh1 : bhh0;
    float bias[4];
#pragma unroll
    for (int g = 0; g < 4; ++g)
        bias[g] = bi[g * 1024 + jbase + jh] + bhp[g * 1024 + jbase + jh];

    float cc[2][4];
#pragma unroll
    for (int mf = 0; mf < 2; ++mf)
#pragma unroll
        for (int r = 0; r < 4; ++r)
            cc[mf][r] = c0[(size_t)(rowbase + mf * 16 + kb * 4 + r) * Hq + jbase + jh];

    floatx4 acc[2][2];
    half8 bf[12][2];                     // ring: 12 slots x 2 frags = 96 VGPRs

    for (int t = -1; t <= 255; ++t) {
        const int active = isL1 ? (t >= 0) : (t < 255);
        if (active) {
#pragma unroll
            for (int mf = 0; mf < 2; ++mf)
#pragma unroll
                for (int n = 0; n < 2; ++n)
                    acc[mf][n] = (floatx4){0.f, 0.f, 0.f, 0.f};

            const _Float16* bp = wlds + kb * 256 + jj * 8;
            // per-lane tiled offset: (rowbase+jj)*32 + kb*8 -> 1KB/wave load
            const size_t loff = (size_t)(rowbase + jj) * 32 + kb * 8;

            if (isL1) {
                // gates1(t) = h_a(t)@Wih1^T + h_b(t-1)@Whh1^T  (64 K-steps)
                const _Float16* apA = bufA + (size_t)(t & 1) * BH + loff;
                const _Float16* apB = bufB + (size_t)((t + 1) & 1) * BH + loff;
#define L1P0(S) (((S) < 32) ? (apA + (size_t)(S) * 8192) : (apB + (size_t)((S) - 32) * 8192))
#define L1P1(S) (L1P0(S) + 512)
#pragma unroll
                for (int i = 0; i < 12; ++i) PISSUE(i, L1P0(i), L1P1(i));
#pragma unroll
                for (int s = 0; s < 52; ++s)
                    PSTEP22(s % 12, L1P0(s + 12), L1P1(s + 12));
                PSTEPW(4, 22);  PSTEPW(5, 20);  PSTEPW(6, 18);  PSTEPW(7, 16);
                PSTEPW(8, 14);  PSTEPW(9, 12);  PSTEPW(10, 10); PSTEPW(11, 8);
                PSTEPW(0, 6);   PSTEPW(1, 4);   PSTEPW(2, 2);   PSTEPW(3, 0);
#undef L1P0
#undef L1P1
            } else {
                // gates0(t+1) = x(t+1)@Wih0^T + h_a(t)@Whh0^T  (36 K-steps)
                const _Float16* apX = xh + (size_t)(t + 1) * 32768 + loff;
                const _Float16* apA = bufA + (size_t)(t & 1) * BH + loff;
#define L0P0(S) (((S) < 4) ? (apX + (size_t)(S) * 8192) : (apA + (size_t)((S) - 4) * 8192))
#define L0P1(S) (L0P0(S) + 512)
#pragma unroll
                for (int i = 0; i < 12; ++i) PISSUE(i, L0P0(i), L0P1(i));
#pragma unroll
                for (int s = 0; s < 24; ++s)
                    PSTEP22(s % 12, L0P0(s + 12), L0P1(s + 12));
                PSTEPW(0, 22);  PSTEPW(1, 20);  PSTEPW(2, 18);  PSTEPW(3, 16);
                PSTEPW(4, 14);  PSTEPW(5, 12);  PSTEPW(6, 10);  PSTEPW(7, 8);
                PSTEPW(8, 6);   PSTEPW(9, 4);   PSTEPW(10, 2);  PSTEPW(11, 0);
#undef L0P0
#undef L0P1
            }

            // ---- elementwise: gate-pair exchange + cell update + h store ----
            // tiled h store: eidx = jtile*8192 + row*32 + jcol (jcol even lane)
            _Float16* hb = isL1 ? (bufB + (size_t)(t & 1) * BH)
                                : (bufA + (size_t)((t + 1) & 1) * BH);
            unsigned* hb32 = (unsigned*)hb;
#pragma unroll
            for (int mf = 0; mf < 2; ++mf) {
#pragma unroll
                for (int r = 0; r < 4; ++r) {
                    float o0 = acc[mf][0][r];       // lo: i, hi: f
                    float o1 = acc[mf][1][r];       // lo: g, hi: o
                    float p0 = __shfl_xor(o0, 8);
                    float p1 = __shfl_xor(o1, 8);
                    float gi = (lo ? o0 : p0) + bias[0];
                    float gf = (lo ? p0 : o0) + bias[1];
                    float gg = (lo ? o1 : p1) + bias[2];
                    float go = (lo ? p1 : o1) + bias[3];
                    float ii = 1.f / (1.f + expf(-gi));
                    float ff = 1.f / (1.f + expf(-gf));
                    float gt = tanhf(gg);
                    float oo = 1.f / (1.f + expf(-go));
                    float cn = ff * cc[mf][r] + ii * gt;
                    cc[mf][r] = cn;
                    float hn = oo * tanhf(cn);

                    union { _Float16 f; unsigned short u; } cv;
                    cv.f = (_Float16)hn;
                    int prt = __shfl_xor((int)cv.u, 1);   // neighbor j^1's bits
                    int row = rowbase + mf * 16 + kb * 4 + r;
                    if (lo && ((jh & 1) == 0)) {
                        unsigned word = (unsigned)cv.u | ((unsigned)prt << 16);
                        size_t eidx = (size_t)jtile * 8192 + (size_t)row * 32 + jcol;
                        __hip_atomic_store(hb32 + (eidx >> 1), word,
                                           __ATOMIC_RELAXED,
                                           __HIP_MEMORY_SCOPE_AGENT);
                    }
                    if (lo && isL1 && t == 255)
                        __hip_atomic_store(hbF + (size_t)row * Hq + jbase + jh,
                                           hn, __ATOMIC_RELAXED,
                                           __HIP_MEMORY_SCOPE_AGENT);
                }
            }
        }

        phasebar(sync, xcdgo, bid, slot, (unsigned)(t + 2));
    }

    // ---- final: out[b][o] = b_out[o] + sum_k hbF[b][k] * Wout[o][k] ----
    // (t=255 phasebar already freshened L2/L1 for hbF's cached reads)
    int gid = bid * 512 + tid;
    if (gid < Bq * 128) {
        int b = gid >> 7, o = gid & 127;
        const floatx4* hr = (const floatx4*)(hbF + (size_t)b * Hq);
        const floatx4* wr = (const floatx4*)(Wout + (size_t)o * Hq);
        float s = bout[o];
#pragma unroll 4
        for (int k = 0; k < Hq / 4; ++k) {
            floatx4 hv = hr[k], wv = wr[k];
            s += hv[0] * wv[0] + hv[1] * wv[1] + hv[2] * wv[2] + hv[3] * wv[3];
        }
        out[gid] = s;
    }
}

// ---------------------------------------------------------------------------
extern "C" void kernel_launch(void* const* d_in, const int* in_sizes, int n_in,
                              void* d_out, int out_size, void* d_ws, size_t ws_size,
                              hipStream_t stream)
{
    (void)in_sizes; (void)n_in;
    float* out = (float*)d_out;

    if (ws_size < (size_t)REQ_WS) {
        float v = -(float)(ws_size >> 20);
        hipLaunchKernelGGL(ws_sentinel_kernel, dim3((out_size + 255) / 256), dim3(256),
                           0, stream, out, out_size, v);
        return;
    }

    const float* x    = (const float*)d_in[0];
    const float* h0   = (const float*)d_in[1];
    const float* c0   = (const float*)d_in[2];
    const float* Wih0 = (const float*)d_in[3];
    const float* Whh0 = (const float*)d_in[4];
    const float* bih0 = (const float*)d_in[5];
    const float* bhh0 = (const float*)d_in[6];
    const float* Wih1 = (const float*)d_in[7];
    const float* Whh1 = (const float*)d_in[8];
    const float* bih1 = (const float*)d_in[9];
    const float* bhh1 = (const float*)d_in[10];
    const float* Wout = (const float*)d_in[11];
    const float* bout = (const float*)d_in[12];

    char* ws = (char*)d_ws;
    _Float16* w1p  = (_Float16*)(ws + OFF_W1);
    _Float16* w0p  = (_Float16*)(ws + OFF_W0);
    _Float16* xh   = (_Float16*)(ws + OFF_XH);
    _Float16* bufA = (_Float16*)(ws + OFF_BA);
    _Float16* bufB = (_Float16*)(ws + OFF_BB);
    float*    hbF  = (float*)   (ws + OFF_HF);
    unsigned* sync = (unsigned*)(ws + OFF_SY);

    long long total = N_W1 + N_W0 + N_XH + N_H;   // 21,757,952 = 84992*256
    hipLaunchKernelGGL(prep_kernel, dim3((unsigned)(total / 256)), dim3(256), 0, stream,
                       x, h0, Wih0, Whh0, Wih1, Whh1, w1p, w0p, xh, bufA, bufB, sync);

    hipLaunchKernelGGL(lstm_main, dim3(256), dim3(512), 0, stream,
                       w1p, w0p, xh, bufA, bufB, hbF, c0,
                       bih0, bhh0, bih1, bhh1, Wout, bout, out, sync);
}